// Round 1
// baseline (2010.501 us; speedup 1.0000x reference)
//
#include <hip/hip_runtime.h>
#include <math.h>

// ---------------------------------------------------------------------------
// Shapes: U=1024 H=16 DH=64 B=2 Q=1024 M=1024 KL=2048 R=2049
// ---------------------------------------------------------------------------

// ---------------- generic f32 GEMM: C[M x N] = A[M x 1024] @ W[1024 x N] ----
// W element [k][n] = Wb[k*5120 + n]  (Wb = kernel + column offset)
// MODE 0: A row r -> A1 + r*1024
// MODE 1: "full" rows: b = r>>11, i = r&2047; i<1024 ? memories : content
// store: col n < splitN -> C0[row*1024 + n], else C1[row*1024 + n - splitN]
template<int MODE>
__global__ __launch_bounds__(256) void gemm_f32(
    const float* __restrict__ A1, const float* __restrict__ A2,
    const float* __restrict__ Wb, float* __restrict__ C0, float* __restrict__ C1,
    int Mrows, int splitN)
{
  __shared__ float As[16][132];  // [k][m]
  __shared__ float Bs[16][132];  // [k][n]
  const int tid = threadIdx.x;
  const int m0 = blockIdx.y * 128;
  const int n0 = blockIdx.x * 128;
  const int tx = tid & 15, ty = tid >> 4;
  float acc[8][8];
#pragma unroll
  for (int i = 0; i < 8; ++i)
#pragma unroll
    for (int j = 0; j < 8; ++j) acc[i][j] = 0.f;

  const int ar = tid >> 2;          // 0..63
  const int ak = (tid & 3) * 4;     // 0,4,8,12
  const int bk = tid >> 5;          // 0..7
  const int bn = (tid & 31) * 4;    // 0..124

  for (int k0 = 0; k0 < 1024; k0 += 16) {
#pragma unroll
    for (int half = 0; half < 2; ++half) {
      int row = m0 + ar + half * 64;
      float4 v = make_float4(0.f, 0.f, 0.f, 0.f);
      if (row < Mrows) {
        const float* src;
        if (MODE == 0) {
          src = A1 + (size_t)row * 1024;
        } else {
          int b = row >> 11, i = row & 2047;
          src = (i < 1024) ? (A1 + (size_t)(b * 1024 + i) * 1024)
                           : (A2 + (size_t)(b * 1024 + (i - 1024)) * 1024);
        }
        v = *reinterpret_cast<const float4*>(src + k0 + ak);
      }
      As[ak + 0][ar + half * 64] = v.x;
      As[ak + 1][ar + half * 64] = v.y;
      As[ak + 2][ar + half * 64] = v.z;
      As[ak + 3][ar + half * 64] = v.w;
      int kk = bk + half * 8;
      float4 w = *reinterpret_cast<const float4*>(Wb + (size_t)(k0 + kk) * 5120 + n0 + bn);
      *reinterpret_cast<float4*>(&Bs[kk][bn]) = w;
    }
    __syncthreads();
#pragma unroll
    for (int k = 0; k < 16; ++k) {
      float a[8], bb[8];
      *reinterpret_cast<float4*>(&a[0]) = *reinterpret_cast<const float4*>(&As[k][ty * 8]);
      *reinterpret_cast<float4*>(&a[4]) = *reinterpret_cast<const float4*>(&As[k][ty * 8 + 4]);
      *reinterpret_cast<float4*>(&bb[0]) = *reinterpret_cast<const float4*>(&Bs[k][tx * 8]);
      *reinterpret_cast<float4*>(&bb[4]) = *reinterpret_cast<const float4*>(&Bs[k][tx * 8 + 4]);
#pragma unroll
      for (int i = 0; i < 8; ++i)
#pragma unroll
        for (int j = 0; j < 8; ++j)
          acc[i][j] = fmaf(a[i], bb[j], acc[i][j]);
    }
    __syncthreads();
  }
#pragma unroll
  for (int i = 0; i < 8; ++i) {
    int row = m0 + ty * 8 + i;
    if (row < Mrows) {
#pragma unroll
      for (int j = 0; j < 8; j += 4) {
        int n = n0 + tx * 8 + j;
        float4 v = make_float4(acc[i][j], acc[i][j + 1], acc[i][j + 2], acc[i][j + 3]);
        if (n < splitN) *reinterpret_cast<float4*>(C0 + (size_t)row * 1024 + n) = v;
        else            *reinterpret_cast<float4*>(C1 + (size_t)row * 1024 + (n - splitN)) = v;
      }
    }
  }
}

// ---------------- qs_seg[b][h][q][s] = sum_d (w_q+bias_s)[h*64+d] * seg_embed[s][h*64+d]
__global__ __launch_bounds__(256) void seg_proj(
    const float* __restrict__ w_q, const float* __restrict__ bias_s,
    const float* __restrict__ seg_embed, float* __restrict__ qs)
{
  int idx = blockIdx.x * 256 + threadIdx.x;   // (b*16+h)*1024 + q
  int q = idx & 1023, h = (idx >> 10) & 15, b = idx >> 14;
  const float* wp = w_q + (size_t)(b * 1024 + q) * 1024 + h * 64;
  const float* bp = bias_s + h * 64;
  const float* e0 = seg_embed + h * 64;
  const float* e1 = seg_embed + 1024 + h * 64;
  float s0 = 0.f, s1 = 0.f;
#pragma unroll 4
  for (int d = 0; d < 64; ++d) {
    float v = wp[d] + bp[d];
    s0 = fmaf(v, e0[d], s0);
    s1 = fmaf(v, e1[d], s1);
  }
  qs[(size_t)idx * 2 + 0] = s0;
  qs[(size_t)idx * 2 + 1] = s1;
}

// ---------------- fused attention ------------------------------------------
// block = 256 threads, handles (b, h, 32 q-rows); iterates 64 k-tiles of 32.
// rel_shift: for score (i,j): diff=j-i;  diff<=1024 -> q_r[i]  . w_r[diff+1024]
//                                        diff>=1025 -> q_r[i+1]. w_r[diff-1025]
// both map to band-local row 31 + jloc - iloc of staged bands A/B.
__global__ __launch_bounds__(256) void attn_fused(
    const float* __restrict__ w_q, const float* __restrict__ w_k,
    const float* __restrict__ w_v, const float* __restrict__ w_rh,
    const float* __restrict__ qs_seg, const float* __restrict__ seg_mat,
    const float* __restrict__ perm, const float* __restrict__ bias_c,
    const float* __restrict__ bias_r, float* __restrict__ attn_out)
{
  const int qt = blockIdx.x;   // 0..31
  const int h  = blockIdx.y;   // 0..15
  const int b  = blockIdx.z;   // 0..1
  const int qi0 = qt * 32;
  const int tid = threadIdx.x;

  __shared__ float qc[32][68];
  __shared__ float qr[33][68];
  __shared__ float wk[32][68];
  __shared__ float wv[32][68];
  __shared__ float wr2[2][64][68];
  __shared__ float se[32][36];
  __shared__ float fac[32], mnew[32], linv[32];
  __shared__ float qs2[32][2];

  // ---- stage q tiles (with biases) ----
  for (int idx = tid; idx < 32 * 16; idx += 256) {
    int r = idx >> 4, d4 = (idx & 15) * 4;
    const float* src = w_q + (size_t)(b * 1024 + qi0 + r) * 1024 + h * 64 + d4;
    float4 v  = *reinterpret_cast<const float4*>(src);
    float4 bc = *reinterpret_cast<const float4*>(bias_c + h * 64 + d4);
    float4 br = *reinterpret_cast<const float4*>(bias_r + h * 64 + d4);
    qc[r][d4 + 0] = v.x + bc.x; qc[r][d4 + 1] = v.y + bc.y;
    qc[r][d4 + 2] = v.z + bc.z; qc[r][d4 + 3] = v.w + bc.w;
    qr[r][d4 + 0] = v.x + br.x; qr[r][d4 + 1] = v.y + br.y;
    qr[r][d4 + 2] = v.z + br.z; qr[r][d4 + 3] = v.w + br.w;
  }
  if (tid < 16) {  // extra q_r row (qi0+32) for the rel-shift spill region
    int d4 = tid * 4;
    float4 v = make_float4(0.f, 0.f, 0.f, 0.f);
    if (qi0 + 32 < 1024)
      v = *reinterpret_cast<const float4*>(w_q + (size_t)(b * 1024 + qi0 + 32) * 1024 + h * 64 + d4);
    float4 br = *reinterpret_cast<const float4*>(bias_r + h * 64 + d4);
    qr[32][d4 + 0] = v.x + br.x; qr[32][d4 + 1] = v.y + br.y;
    qr[32][d4 + 2] = v.z + br.z; qr[32][d4 + 3] = v.w + br.w;
  }
  if (tid < 32) {
    const float* qp = qs_seg + (size_t)(((b * 16 + h) * 1024) + qi0 + tid) * 2;
    qs2[tid][0] = qp[0];
    qs2[tid][1] = qp[1];
  }

  float mrow = -1e30f, lrow = 0.f;  // valid in tid<32
  float o[8];
#pragma unroll
  for (int t = 0; t < 8; ++t) o[t] = 0.f;
  const int prow = tid >> 3;        // PV: row 0..31
  const int pdg  = (tid & 7) * 8;   // PV: col base 0..56
  const int si  = tid >> 3;         // score: row 0..31
  const int sjb = (tid & 7) * 4;    // score: col base 0..28

  for (int kj = 0; kj < 2048; kj += 32) {
    __syncthreads();  // (a) previous tile fully consumed
    // ---- stage K/V tiles ----
    for (int idx = tid; idx < 32 * 16; idx += 256) {
      int r = idx >> 4, d4 = (idx & 15) * 4;
      size_t off = (size_t)(b * 2048 + kj + r) * 1024 + h * 64 + d4;
      *reinterpret_cast<float4*>(&wk[r][d4]) = *reinterpret_cast<const float4*>(w_k + off);
      *reinterpret_cast<float4*>(&wv[r][d4]) = *reinterpret_cast<const float4*>(w_v + off);
    }
    // ---- stage w_r bands ----
    const int cA0 = 993 + kj - qi0;
    const int cB0 = kj - qi0 - 1056;
    const bool useA = (kj - qi0 - 31) <= 1024;
    const bool useB = (kj - qi0 + 31) >= 1025;
    if (useA) {
      for (int idx = tid; idx < 64 * 16; idx += 256) {
        int r = idx >> 4, d4 = (idx & 15) * 4;
        int c = cA0 + r; c = c < 0 ? 0 : (c > 2048 ? 2048 : c);
        *reinterpret_cast<float4*>(&wr2[0][r][d4]) =
          *reinterpret_cast<const float4*>(w_rh + (size_t)(b * 2049 + c) * 1024 + h * 64 + d4);
      }
    }
    if (useB) {
      for (int idx = tid; idx < 64 * 16; idx += 256) {
        int r = idx >> 4, d4 = (idx & 15) * 4;
        int c = cB0 + r; c = c < 0 ? 0 : (c > 2048 ? 2048 : c);
        *reinterpret_cast<float4*>(&wr2[1][r][d4]) =
          *reinterpret_cast<const float4*>(w_rh + (size_t)(b * 2049 + c) * 1024 + h * 64 + d4);
      }
    }
    __syncthreads();  // (b)

    // ---- scores ----
    {
      const int i_g = qi0 + si;
      float q0 = qs2[si][0], q1 = qs2[si][1];
      const float* sp = seg_mat + ((size_t)(b * 1024 + i_g) * 2048 + kj + sjb) * 2;
      float4 sA = *reinterpret_cast<const float4*>(sp);
      float4 sB = *reinterpret_cast<const float4*>(sp + 4);
      float s[4];
      s[0] = sA.x * q0 + sA.y * q1;
      s[1] = sA.z * q0 + sA.w * q1;
      s[2] = sB.x * q0 + sB.y * q1;
      s[3] = sB.z * q0 + sB.w * q1;
      float dc[4] = {0.f, 0.f, 0.f, 0.f}, dr[4] = {0.f, 0.f, 0.f, 0.f};
      const int diff0 = kj + sjb - i_g;
#pragma unroll 4
      for (int d4 = 0; d4 < 64; d4 += 4) {
        float4 qc4 = *reinterpret_cast<const float4*>(&qc[si][d4]);
        float4 qr0 = *reinterpret_cast<const float4*>(&qr[si][d4]);
        float4 qr1 = *reinterpret_cast<const float4*>(&qr[si + 1][d4]);
#pragma unroll
        for (int jl = 0; jl < 4; ++jl) {
          float4 k4 = *reinterpret_cast<const float4*>(&wk[sjb + jl][d4]);
          dc[jl] = fmaf(qc4.x, k4.x, fmaf(qc4.y, k4.y, fmaf(qc4.z, k4.z, fmaf(qc4.w, k4.w, dc[jl]))));
          const bool mn = (diff0 + jl) <= 1024;
          const float4 r4 = *reinterpret_cast<const float4*>(&wr2[mn ? 0 : 1][31 + sjb + jl - si][d4]);
          const float4 qq = mn ? qr0 : qr1;
          dr[jl] = fmaf(qq.x, r4.x, fmaf(qq.y, r4.y, fmaf(qq.z, r4.z, fmaf(qq.w, r4.w, dr[jl]))));
        }
      }
#pragma unroll
      for (int jl = 0; jl < 4; ++jl)
        se[si][sjb + jl] = (s[jl] + dc[jl] + dr[jl]) * 0.125f;
    }
    __syncthreads();  // (c)

    float facr = 0.f;
    if (tid < 32) {
      float tm = -1e30f;
#pragma unroll 8
      for (int j = 0; j < 32; ++j) tm = fmaxf(tm, se[tid][j]);
      float mn2 = fmaxf(mrow, tm);
      facr = __expf(mrow - mn2);
      mrow = mn2;
      fac[tid] = facr;
      mnew[tid] = mn2;
    }
    __syncthreads();  // (d)

    // ---- e = exp(s - m) * perm ----
    {
      const int i_g = qi0 + si;
      float m2 = mnew[si];
      const float* pp = perm + (size_t)(b * 1024 + i_g) * 2048 + kj + sjb;
      float4 p4 = *reinterpret_cast<const float4*>(pp);
      float e0 = __expf(se[si][sjb + 0] - m2) * p4.x;
      float e1 = __expf(se[si][sjb + 1] - m2) * p4.y;
      float e2 = __expf(se[si][sjb + 2] - m2) * p4.z;
      float e3 = __expf(se[si][sjb + 3] - m2) * p4.w;
      se[si][sjb + 0] = e0; se[si][sjb + 1] = e1;
      se[si][sjb + 2] = e2; se[si][sjb + 3] = e3;
    }
    __syncthreads();  // (e)

    if (tid < 32) {
      float rs = 0.f;
#pragma unroll 8
      for (int j = 0; j < 32; ++j) rs += se[tid][j];
      lrow = lrow * facr + rs;
    }
    // ---- PV ----
    {
      float f = fac[prow];
#pragma unroll
      for (int t = 0; t < 8; ++t) o[t] *= f;
#pragma unroll 4
      for (int j4 = 0; j4 < 32; j4 += 4) {
        float4 e4 = *reinterpret_cast<const float4*>(&se[prow][j4]);
#pragma unroll
        for (int jj = 0; jj < 4; ++jj) {
          float ev = (&e4.x)[jj];
          float4 v0 = *reinterpret_cast<const float4*>(&wv[j4 + jj][pdg]);
          float4 v1 = *reinterpret_cast<const float4*>(&wv[j4 + jj][pdg + 4]);
          o[0] = fmaf(ev, v0.x, o[0]); o[1] = fmaf(ev, v0.y, o[1]);
          o[2] = fmaf(ev, v0.z, o[2]); o[3] = fmaf(ev, v0.w, o[3]);
          o[4] = fmaf(ev, v1.x, o[4]); o[5] = fmaf(ev, v1.y, o[5]);
          o[6] = fmaf(ev, v1.z, o[6]); o[7] = fmaf(ev, v1.w, o[7]);
        }
      }
    }
  }

  if (tid < 32) linv[tid] = 1.f / (lrow + 1e-7f);
  __syncthreads();
  {
    float s = linv[prow];
    float4 v0 = make_float4(o[0] * s, o[1] * s, o[2] * s, o[3] * s);
    float4 v1 = make_float4(o[4] * s, o[5] * s, o[6] * s, o[7] * s);
    float* dst = attn_out + (size_t)(b * 1024 + qi0 + prow) * 1024 + h * 64 + pdg;
    *reinterpret_cast<float4*>(dst) = v0;
    *reinterpret_cast<float4*>(dst + 4) = v1;
  }
}

// ---------------------------------------------------------------------------
extern "C" void kernel_launch(void* const* d_in, const int* in_sizes, int n_in,
                              void* d_out, int out_size, void* d_ws, size_t ws_size,
                              hipStream_t stream)
{
  (void)in_sizes; (void)n_in; (void)out_size; (void)ws_size;
  const float* inputs    = (const float*)d_in[0];
  const float* content   = (const float*)d_in[1];
  const float* memories  = (const float*)d_in[2];
  const float* relatives = (const float*)d_in[3];
  const float* seg_mat   = (const float*)d_in[4];
  const float* seg_embed = (const float*)d_in[5];
  const float* bias_c    = (const float*)d_in[6];
  const float* bias_r    = (const float*)d_in[7];
  const float* bias_s    = (const float*)d_in[8];
  const float* perm      = (const float*)d_in[9];
  const float* kern      = (const float*)d_in[10];
  float* out = (float*)d_out;

  float* ws    = (float*)d_ws;
  float* w_q   = ws;                  // 2*1024*1024          = 2,097,152
  float* w_k   = w_q  + 2097152;      // 2*2048*1024          = 4,194,304
  float* w_v   = w_k  + 4194304;      // 2*2048*1024          = 4,194,304
  float* w_rh  = w_v  + 4194304;      // 2*2049*1024          = 4,196,352
  float* a_out = w_rh + 4196352;      // 2*1024*1024          = 2,097,152
  float* qs    = a_out + 2097152;     // 2*16*1024*2          = 65,536

  dim3 blk(256);
  // w_q = inputs @ kernel[:, :1024]
  gemm_f32<0><<<dim3(8, 16), blk, 0, stream>>>(inputs, nullptr, kern + 0, w_q, w_q, 2048, 1024);
  // w_kv = [memories;content] @ kernel[:, 1024:3072] -> w_k | w_v
  gemm_f32<1><<<dim3(16, 32), blk, 0, stream>>>(memories, content, kern + 1024, w_k, w_v, 4096, 1024);
  // w_r = relatives @ kernel[:, 3072:4096]
  gemm_f32<0><<<dim3(8, 33), blk, 0, stream>>>(relatives, nullptr, kern + 3072, w_rh, w_rh, 4098, 1024);
  // segment projections (needs w_q)
  seg_proj<<<dim3(128), blk, 0, stream>>>(w_q, bias_s, seg_embed, qs);
  // fused attention
  attn_fused<<<dim3(32, 16, 2), blk, 0, stream>>>(w_q, w_k, w_v, w_rh, qs, seg_mat, perm,
                                                  bias_c, bias_r, a_out);
  // out = a_out @ kernel[:, 4096:5120]
  gemm_f32<0><<<dim3(8, 16), blk, 0, stream>>>(a_out, nullptr, kern + 4096, out, out, 2048, 1024);
}

// Round 2
// 325.748 us; speedup vs baseline: 6.1719x; 6.1719x over previous
//
#include <hip/hip_runtime.h>

typedef __bf16 bf16;
typedef unsigned short u16;
typedef unsigned int u32;
typedef __attribute__((ext_vector_type(8))) __bf16 bf16x8;
typedef __attribute__((ext_vector_type(4))) __bf16 bf16x4;
typedef __attribute__((ext_vector_type(4))) float f32x4;
typedef __attribute__((ext_vector_type(8))) float f32x8;

// slot index (16B units) for 8-seg rows (64 bf16/row), XOR-swizzled
#define SWZ(r, s) (((r) << 3) + ((s) ^ ((r) & 7)))
// slot index for 4-seg rows (32 bf16/row), XOR-swizzled
#define GSW(r, s) (((r) << 2) + ((s) ^ (((r) >> 1) & 3)))

__device__ __forceinline__ f32x4 mfma16(bf16x8 a, bf16x8 b, f32x4 c) {
  return __builtin_amdgcn_mfma_f32_16x16x32_bf16(a, b, c, 0, 0, 0);
}
__device__ __forceinline__ void gld16(const void* g, void* l) {
  __builtin_amdgcn_global_load_lds((const __attribute__((address_space(1))) void*)g,
                                   (__attribute__((address_space(3))) void*)l, 16, 0, 0);
}

// ---------------------------------------------------------------------------
// prep kernels
// ---------------------------------------------------------------------------
__global__ __launch_bounds__(256) void cvt_bf16(const float* __restrict__ s,
                                                bf16* __restrict__ d, int n) {
  int i = (blockIdx.x * 256 + threadIdx.x) * 4;
  if (i < n) {
    f32x4 v = *reinterpret_cast<const f32x4*>(s + i);
    *reinterpret_cast<bf16x4*>(d + i) = __builtin_convertvector(v, bf16x4);
  }
}

// full = concat(memories, content) per batch -> bf16 [2][2048][1024]
__global__ __launch_bounds__(256) void cvt_full(const float* __restrict__ mem,
                                                const float* __restrict__ cont,
                                                bf16* __restrict__ d) {
  size_t i = ((size_t)blockIdx.x * 256 + threadIdx.x) * 4;
  int row = (int)(i >> 10), col = (int)(i & 1023);
  int b = row >> 11, r = row & 2047;
  const float* src = (r < 1024)
      ? (mem  + (((size_t)(b << 10) + r)        << 10) + col)
      : (cont + (((size_t)(b << 10) + (r - 1024)) << 10) + col);
  f32x4 v = *reinterpret_cast<const f32x4*>(src);
  *reinterpret_cast<bf16x4*>(d + i) = __builtin_convertvector(v, bf16x4);
}

// kernel f32 [1024][5120] -> kT bf16 [5120][1024]
__global__ __launch_bounds__(256) void kT_cvt(const float* __restrict__ K,
                                              bf16* __restrict__ KT) {
  __shared__ float t[64][68];
  const int n0 = blockIdx.x << 6, k0 = blockIdx.y << 6;
  for (int idx = threadIdx.x; idx < 1024; idx += 256) {
    int r = idx >> 4, c4 = (idx & 15) << 2;
    f32x4 v = *reinterpret_cast<const f32x4*>(K + (size_t)(k0 + r) * 5120 + n0 + c4);
    t[r][c4] = v.x; t[r][c4 + 1] = v.y; t[r][c4 + 2] = v.z; t[r][c4 + 3] = v.w;
  }
  __syncthreads();
  for (int idx = threadIdx.x; idx < 1024; idx += 256) {
    int r = idx >> 4, c4 = (idx & 15) << 2;  // r = n-local, c4 = k-local
    bf16x4 o = { (bf16)t[c4][r], (bf16)t[c4 + 1][r], (bf16)t[c4 + 2][r], (bf16)t[c4 + 3][r] };
    *reinterpret_cast<bf16x4*>(KT + (size_t)(n0 + r) * 1024 + k0 + c4) = o;
  }
}

// qs[b][h][q][s] = sum_d (w_q+bias_s)[h*64+d] * segment_embed[s][h*64+d]
__global__ __launch_bounds__(256) void seg_proj(const bf16* __restrict__ w_q,
                                                const float* __restrict__ bias_s,
                                                const float* __restrict__ seg_embed,
                                                float* __restrict__ qs) {
  int idx = blockIdx.x * 256 + threadIdx.x;  // (b*16+h)*1024 + q
  int q = idx & 1023, h = (idx >> 10) & 15, b = idx >> 14;
  const bf16* wp = w_q + (((size_t)(b << 10) + q) << 10) + (h << 6);
  const float* bp = bias_s + (h << 6);
  const float* e0 = seg_embed + (h << 6);
  const float* e1 = seg_embed + 1024 + (h << 6);
  float s0 = 0.f, s1 = 0.f;
#pragma unroll 8
  for (int d = 0; d < 64; ++d) {
    float v = (float)wp[d] + bp[d];
    s0 = fmaf(v, e0[d], s0);
    s1 = fmaf(v, e1[d], s1);
  }
  qs[((size_t)idx << 1) + 0] = s0;
  qs[((size_t)idx << 1) + 1] = s1;
}

// ---------------------------------------------------------------------------
// MFMA GEMM: C[M x N] = A[M x 1024](bf16) @ BT[N x 1024]^T(bf16)
// OUT_MODE: 0 = f32 store, 1 = bf16 store, 2 = f32 accumulate
// col < splitN -> C0, else C1 (both row stride 1024)
// ---------------------------------------------------------------------------
template<int OUT_MODE>
__global__ __launch_bounds__(256) void gemm_mfma(const bf16* __restrict__ A,
                                                 const bf16* __restrict__ BT,
                                                 void* __restrict__ C0v,
                                                 void* __restrict__ C1v,
                                                 int Mrows, int splitN) {
  __shared__ bf16 As[4096];
  __shared__ bf16 Bs[4096];
  const int tid = threadIdx.x;
  const int m0 = blockIdx.y << 7, n0 = blockIdx.x << 7;
  const int l = tid & 63, w = tid >> 6;
  const int wm = (w >> 1) << 6, wn = (w & 1) << 6;
  const int lc = l & 15, l16 = l >> 4;
  f32x4 acc[4][4] = {};
  const int r0 = tid >> 2, r1 = r0 + 64;
  const int sq = tid & 3;
  const int g0 = (sq ^ ((r0 >> 1) & 3)) << 3;  // pre-swizzled global seg (elems)
  // note ((r1>>1)&3) == ((r0>>1)&3) since r1 = r0+64

  for (int k0 = 0; k0 < 1024; k0 += 32) {
    __syncthreads();
    gld16(A  + (size_t)(m0 + r0) * 1024 + k0 + g0, &As[tid << 3]);
    gld16(BT + (size_t)(n0 + r0) * 1024 + k0 + g0, &Bs[tid << 3]);
    gld16(A  + (size_t)(m0 + r1) * 1024 + k0 + g0, &As[(tid + 256) << 3]);
    gld16(BT + (size_t)(n0 + r1) * 1024 + k0 + g0, &Bs[(tid + 256) << 3]);
    __syncthreads();
    bf16x8 af[4], bfv[4];
#pragma unroll
    for (int m = 0; m < 4; ++m)
      af[m] = *reinterpret_cast<const bf16x8*>(&As[GSW(wm + (m << 4) + lc, l16) << 3]);
#pragma unroll
    for (int n = 0; n < 4; ++n)
      bfv[n] = *reinterpret_cast<const bf16x8*>(&Bs[GSW(wn + (n << 4) + lc, l16) << 3]);
#pragma unroll
    for (int m = 0; m < 4; ++m)
#pragma unroll
      for (int n = 0; n < 4; ++n)
        acc[m][n] = mfma16(af[m], bfv[n], acc[m][n]);
  }
#pragma unroll
  for (int m = 0; m < 4; ++m) {
    const int rbase = m0 + wm + (m << 4) + (l16 << 2);
#pragma unroll
    for (int n = 0; n < 4; ++n) {
      const int col = n0 + wn + (n << 4) + lc;
      const int cc = (col < splitN) ? col : (col - splitN);
      void* Cv = (col < splitN) ? C0v : C1v;
#pragma unroll
      for (int r = 0; r < 4; ++r) {
        const int row = rbase + r;
        if (row < Mrows) {
          const float v = acc[m][n][r];
          const size_t off = ((size_t)row << 10) + cc;
          if (OUT_MODE == 1)      ((bf16*)Cv)[off] = (bf16)v;
          else if (OUT_MODE == 0) ((float*)Cv)[off] = v;
          else                    ((float*)Cv)[off] += v;
        }
      }
    }
  }
}

// ---------------------------------------------------------------------------
// fused attention, MFMA. block = (b, h, 64 q-rows); 64 k-steps of 32.
// rel shift (verified round 1): diff=j-i (global); diff<=1024 -> q_r[i].w_r[diff+1024]
//                               diff>=1025 -> q_r[i+1].w_r[diff-1025]
// band-local row = 63 + jl - il; band A base = kj-qi0+961, band B base = kj-qi0-1088
// ---------------------------------------------------------------------------
__global__ __launch_bounds__(256) void attn_mfma(
    const bf16* __restrict__ w_q, const bf16* __restrict__ w_k,
    const bf16* __restrict__ w_v, const bf16* __restrict__ w_rh,
    const float* __restrict__ qs_seg, const float* __restrict__ seg_mat,
    const float* __restrict__ perm, const float* __restrict__ bias_c,
    const float* __restrict__ bias_r, bf16* __restrict__ a_hi,
    bf16* __restrict__ a_lo) {
  const int h = blockIdx.x, qt = blockIdx.y, b = blockIdx.z;
  const int qi0 = qt << 6;
  const int tid = threadIdx.x;
  const int w = tid >> 6, l = tid & 63;
  const int lc = l & 15, l16 = l >> 4;
  const int ai = tid >> 2, aj0 = (tid & 3) << 3;  // assembly row / col base

  __shared__ bf16 qc[64 * 64];        // swizzled
  __shared__ bf16 qr[65 * 64];        // swizzled (+1 row for spill)
  __shared__ bf16 kt[32 * 64];        // swizzled
  __shared__ u16  vt[64 * 40];        // V^T, padded rows (40)
  __shared__ bf16 wb[2 * 96 * 64];    // w_r bands, swizzled
  __shared__ bf16 pl[64 * 40];        // P, padded rows (40)
  __shared__ float S[64 * 33];
  __shared__ float ARl[4 * 784];      // per-wave 16 x 49
  __shared__ float mrowl[64], lrowl[64], facl[64], qs0l[64], qs1l[64];

  // ---- stage q tiles (bias added, back to bf16, swizzled) ----
  for (int c = tid; c < 520; c += 256) {
    int r = c >> 3, s = c & 7;
    int grow = qi0 + r; if (grow > 1023) grow = 1023;
    bf16x8 qv = *reinterpret_cast<const bf16x8*>(
        w_q + (((size_t)(b << 10) + grow) << 10) + (h << 6) + (s << 3));
    f32x8 qf = __builtin_convertvector(qv, f32x8);
    f32x8 brv = *reinterpret_cast<const f32x8*>(bias_r + (h << 6) + (s << 3));
    *reinterpret_cast<bf16x8*>(&qr[SWZ(r, s) << 3]) = __builtin_convertvector(qf + brv, bf16x8);
    if (c < 512) {
      f32x8 bcv = *reinterpret_cast<const f32x8*>(bias_c + (h << 6) + (s << 3));
      *reinterpret_cast<bf16x8*>(&qc[SWZ(r, s) << 3]) = __builtin_convertvector(qf + bcv, bf16x8);
    }
  }
  if (tid < 64) {
    mrowl[tid] = -1e30f;
    lrowl[tid] = 0.f;
    const float* qp = qs_seg + ((((size_t)((b << 4) + h) << 10) + qi0 + tid) << 1);
    qs0l[tid] = qp[0];
    qs1l[tid] = qp[1];
  }

  f32x4 o[4] = {};

  for (int kj = 0; kj < 2048; kj += 32) {
    const int rel0 = kj - qi0;
    const bool strad = (rel0 >= 994) && (rel0 <= 1087);
    const int firstVar = (rel0 >= 1088) ? 1 : 0;
    __syncthreads();  // (a) all waves done with previous tile LDS

    // ---- stage K tile (global_load_lds, source pre-swizzled) ----
    {
      int r = tid >> 3, s = tid & 7;
      gld16(w_k + ((size_t)((b << 11) + kj + r) << 10) + (h << 6) + ((s ^ (r & 7)) << 3),
            &kt[tid << 3]);
    }
    // ---- stage w_r band(s) ----
    {
      const int cbase = firstVar ? (rel0 - 1088) : (rel0 + 961);
      for (int c = tid; c < 768; c += 256) {
        int r = c >> 3, s = c & 7;
        int grow = cbase + r; grow = grow < 0 ? 0 : (grow > 2048 ? 2048 : grow);
        gld16(w_rh + ((size_t)(b * 2049 + grow) << 10) + (h << 6) + ((s ^ (r & 7)) << 3),
              &wb[c << 3]);
      }
      if (strad) {
        const int cbase2 = rel0 - 1088;
        for (int c = tid; c < 768; c += 256) {
          int r = c >> 3, s = c & 7;
          int grow = cbase2 + r; grow = grow < 0 ? 0 : (grow > 2048 ? 2048 : grow);
          gld16(w_rh + ((size_t)(b * 2049 + grow) << 10) + (h << 6) + ((s ^ (r & 7)) << 3),
                &wb[6144 + (c << 3)]);
        }
      }
    }
    // ---- stage V^T (register transpose) ----
    {
      const int kv2 = (tid >> 4) << 1, d4 = (tid & 15) << 2;
      const u16* vp = (const u16*)w_v + ((size_t)((b << 11) + kj + kv2) << 10) + (h << 6) + d4;
      uint2 ra = *reinterpret_cast<const uint2*>(vp);
      uint2 rb = *reinterpret_cast<const uint2*>(vp + 1024);
      u32* vt32 = reinterpret_cast<u32*>(&vt[0]);
      vt32[((d4 + 0) * 40 + kv2) >> 1] = (ra.x & 0xffffu) | (rb.x << 16);
      vt32[((d4 + 1) * 40 + kv2) >> 1] = (ra.x >> 16) | (rb.x & 0xffff0000u);
      vt32[((d4 + 2) * 40 + kv2) >> 1] = (ra.y & 0xffffu) | (rb.y << 16);
      vt32[((d4 + 3) * 40 + kv2) >> 1] = (ra.y >> 16) | (rb.y & 0xffff0000u);
    }
    // ---- prefetch seg/perm for this tile into regs ----
    const size_t soff = ((size_t)((b << 10) + qi0 + ai) * 2048 + kj + aj0) * 2;
    f32x4 sg0 = *reinterpret_cast<const f32x4*>(seg_mat + soff);
    f32x4 sg1 = *reinterpret_cast<const f32x4*>(seg_mat + soff + 4);
    f32x4 sg2 = *reinterpret_cast<const f32x4*>(seg_mat + soff + 8);
    f32x4 sg3 = *reinterpret_cast<const f32x4*>(seg_mat + soff + 12);
    const size_t poff = (size_t)((b << 10) + qi0 + ai) * 2048 + kj + aj0;
    f32x4 pm0 = *reinterpret_cast<const f32x4*>(perm + poff);
    f32x4 pm1 = *reinterpret_cast<const f32x4*>(perm + poff + 4);

    __syncthreads();  // (b) tiles ready (drains vmcnt)

    // ---- phase 1: MFMA context + AR(first variant) ----
    const int qrow = (w << 4) + lc;
    const int wbase = 48 - (w << 4);
    {
      bf16x8 aq0 = *reinterpret_cast<const bf16x8*>(&qc[SWZ(qrow, l16) << 3]);
      bf16x8 aq1 = *reinterpret_cast<const bf16x8*>(&qc[SWZ(qrow, l16 + 4) << 3]);
      f32x4 sc0 = {0.f, 0.f, 0.f, 0.f}, sc1 = {0.f, 0.f, 0.f, 0.f};
      bf16x8 b0 = *reinterpret_cast<const bf16x8*>(&kt[SWZ(lc, l16) << 3]);
      bf16x8 b1 = *reinterpret_cast<const bf16x8*>(&kt[SWZ(lc, l16 + 4) << 3]);
      sc0 = mfma16(aq0, b0, sc0); sc0 = mfma16(aq1, b1, sc0);
      b0 = *reinterpret_cast<const bf16x8*>(&kt[SWZ(16 + lc, l16) << 3]);
      b1 = *reinterpret_cast<const bf16x8*>(&kt[SWZ(16 + lc, l16 + 4) << 3]);
      sc1 = mfma16(aq0, b0, sc1); sc1 = mfma16(aq1, b1, sc1);

      const int qrr = qrow + firstVar;
      bf16x8 ar0 = *reinterpret_cast<const bf16x8*>(&qr[SWZ(qrr, l16) << 3]);
      bf16x8 ar1 = *reinterpret_cast<const bf16x8*>(&qr[SWZ(qrr, l16 + 4) << 3]);
#pragma unroll
      for (int c3 = 0; c3 < 3; ++c3) {
        const int brow = wbase + (c3 << 4) + lc;
        bf16x8 w0 = *reinterpret_cast<const bf16x8*>(&wb[SWZ(brow, l16) << 3]);
        bf16x8 w1 = *reinterpret_cast<const bf16x8*>(&wb[SWZ(brow, l16 + 4) << 3]);
        f32x4 a_ = {0.f, 0.f, 0.f, 0.f};
        a_ = mfma16(ar0, w0, a_); a_ = mfma16(ar1, w1, a_);
#pragma unroll
        for (int r = 0; r < 4; ++r)
          ARl[w * 784 + ((l16 << 2) + r) * 49 + (c3 << 4) + lc] = a_[r];
      }
#pragma unroll
      for (int r = 0; r < 4; ++r) {
        const int row = (w << 4) + (l16 << 2) + r;
        S[row * 33 + lc] = sc0[r];
        S[row * 33 + 16 + lc] = sc1[r];
      }
    }
    __syncthreads();  // (c)

    if (strad) {
      // add main-region rel (variant A, currently in ARl) into S
      const int ilw = ai & 15, wq = ai >> 4;
#pragma unroll
      for (int jj = 0; jj < 8; ++jj) {
        const int j = aj0 + jj;
        if (rel0 + j - ai <= 1024)
          S[ai * 33 + j] += ARl[wq * 784 + ilw * 49 + 15 + j - ilw];
      }
      __syncthreads();
      // recompute ARl with variant B (q_r[i+1], band B in wb[1])
      const int qrr = qrow + 1;
      bf16x8 ar0 = *reinterpret_cast<const bf16x8*>(&qr[SWZ(qrr, l16) << 3]);
      bf16x8 ar1 = *reinterpret_cast<const bf16x8*>(&qr[SWZ(qrr, l16 + 4) << 3]);
#pragma unroll
      for (int c3 = 0; c3 < 3; ++c3) {
        const int brow = wbase + (c3 << 4) + lc;
        bf16x8 w0 = *reinterpret_cast<const bf16x8*>(&wb[6144 + (SWZ(brow, l16) << 3)]);
        bf16x8 w1 = *reinterpret_cast<const bf16x8*>(&wb[6144 + (SWZ(brow, l16 + 4) << 3)]);
        f32x4 a_ = {0.f, 0.f, 0.f, 0.f};
        a_ = mfma16(ar0, w0, a_); a_ = mfma16(ar1, w1, a_);
#pragma unroll
        for (int r = 0; r < 4; ++r)
          ARl[w * 784 + ((l16 << 2) + r) * 49 + (c3 << 4) + lc] = a_[r];
      }
      __syncthreads();
    }

    // ---- phase 2: assemble scores + online softmax + write P ----
    {
      const int ilw = ai & 15, wq = ai >> 4;
      float sege[16], pmv[8];
      *reinterpret_cast<f32x4*>(&sege[0])  = sg0;
      *reinterpret_cast<f32x4*>(&sege[4])  = sg1;
      *reinterpret_cast<f32x4*>(&sege[8])  = sg2;
      *reinterpret_cast<f32x4*>(&sege[12]) = sg3;
      *reinterpret_cast<f32x4*>(&pmv[0]) = pm0;
      *reinterpret_cast<f32x4*>(&pmv[4]) = pm1;
      const float q0 = qs0l[ai], q1 = qs1l[ai];
      float sv[8];
      float tm = -1e30f;
#pragma unroll
      for (int jj = 0; jj < 8; ++jj) {
        const int j = aj0 + jj;
        float rel;
        if (!strad) rel = ARl[wq * 784 + ilw * 49 + 15 + j - ilw];
        else rel = (rel0 + j - ai >= 1025) ? ARl[wq * 784 + ilw * 49 + 15 + j - ilw] : 0.f;
        const float asg = sege[2 * jj] * q0 + sege[2 * jj + 1] * q1;
        sv[jj] = (S[ai * 33 + j] + rel + asg) * 0.125f;
        tm = fmaxf(tm, sv[jj]);
      }
      tm = fmaxf(tm, __shfl_xor(tm, 1));
      tm = fmaxf(tm, __shfl_xor(tm, 2));
      const float mold = mrowl[ai];
      const float mn2 = fmaxf(mold, tm);
      const float facr = __expf(mold - mn2);
      float rs = 0.f;
      bf16x8 pv_;
#pragma unroll
      for (int jj = 0; jj < 8; ++jj) {
        const float e = __expf(sv[jj] - mn2) * pmv[jj];
        rs += e;
        pv_[jj] = (bf16)e;
      }
      rs += __shfl_xor(rs, 1);
      rs += __shfl_xor(rs, 2);
      *reinterpret_cast<bf16x8*>(&pl[ai * 40 + aj0]) = pv_;
      if ((tid & 3) == 0) {
        mrowl[ai] = mn2;
        facl[ai] = facr;
        lrowl[ai] = lrowl[ai] * facr + rs;
      }
    }
    __syncthreads();  // (d) P + fac ready

    // ---- phase 3: PV ----
    {
      float fr[4];
#pragma unroll
      for (int r = 0; r < 4; ++r) fr[r] = facl[(w << 4) + (l16 << 2) + r];
#pragma unroll
      for (int n = 0; n < 4; ++n)
#pragma unroll
        for (int r = 0; r < 4; ++r) o[n][r] *= fr[r];
      bf16x8 ap = *reinterpret_cast<const bf16x8*>(&pl[((w << 4) + lc) * 40 + (l16 << 3)]);
#pragma unroll
      for (int n = 0; n < 4; ++n) {
        bf16x8 bv = *reinterpret_cast<const bf16x8*>(&vt[((n << 4) + lc) * 40 + (l16 << 3)]);
        o[n] = mfma16(ap, bv, o[n]);
      }
    }
  }

  __syncthreads();
  // ---- epilogue: normalize, split hi/lo bf16 store ----
  {
    float inv[4];
#pragma unroll
    for (int r = 0; r < 4; ++r)
      inv[r] = 1.f / (lrowl[(w << 4) + (l16 << 2) + r] + 1e-7f);
#pragma unroll
    for (int n = 0; n < 4; ++n) {
#pragma unroll
      for (int r = 0; r < 4; ++r) {
        const int row = qi0 + (w << 4) + (l16 << 2) + r;
        const float v = o[n][r] * inv[r];
        const bf16 hi = (bf16)v;
        const float lof = v - (float)hi;
        const size_t off = (((size_t)(b << 10) + row) << 10) + (h << 6) + (n << 4) + lc;
        a_hi[off] = hi;
        a_lo[off] = (bf16)lof;
      }
    }
  }
}

// ---------------------------------------------------------------------------
extern "C" void kernel_launch(void* const* d_in, const int* in_sizes, int n_in,
                              void* d_out, int out_size, void* d_ws, size_t ws_size,
                              hipStream_t stream) {
  (void)in_sizes; (void)n_in; (void)out_size; (void)ws_size;
  const float* inputs    = (const float*)d_in[0];
  const float* content   = (const float*)d_in[1];
  const float* memories  = (const float*)d_in[2];
  const float* relatives = (const float*)d_in[3];
  const float* seg_mat   = (const float*)d_in[4];
  const float* seg_embed = (const float*)d_in[5];
  const float* bias_c    = (const float*)d_in[6];
  const float* bias_r    = (const float*)d_in[7];
  const float* bias_s    = (const float*)d_in[8];
  const float* perm      = (const float*)d_in[9];
  const float* kern      = (const float*)d_in[10];
  float* out = (float*)d_out;

  char* ws = (char*)d_ws;
  bf16*  in_b   = (bf16*)(ws);                 // 2048x1024            (4 MB)
  bf16*  full_b = (bf16*)(ws + 4194304);       // 4096x1024            (8 MB)
  bf16*  rel_b  = (bf16*)(ws + 12582912);      // 4224x1024 (padded)   (8.65 MB)
  bf16*  kT     = (bf16*)(ws + 21233664);      // 5120x1024            (10.5 MB)
  bf16*  w_q    = (bf16*)(ws + 31719424);      // 2048x1024
  bf16*  w_k    = (bf16*)(ws + 35913728);      // 4096x1024
  bf16*  w_v    = (bf16*)(ws + 44302336);      // 4096x1024
  bf16*  w_rh   = (bf16*)(ws + 52690944);      // 4098x1024
  bf16*  a_hi   = (bf16*)(ws + 61083648);      // 2048x1024
  float* qs     = (float*)(ws + 65277952);     // 2x16x1024x2
  bf16*  a_lo   = in_b;  // reuse: inputs_bf16 dead after w_q GEMM

  dim3 blk(256);
  cvt_bf16<<<2048, blk, 0, stream>>>(inputs, in_b, 2097152);
  cvt_full<<<4096, blk, 0, stream>>>(memories, content, full_b);
  cvt_bf16<<<4098, blk, 0, stream>>>(relatives, rel_b, 4196352);
  kT_cvt<<<dim3(80, 16), blk, 0, stream>>>(kern, kT);

  // projections
  gemm_mfma<1><<<dim3(8, 16),  blk, 0, stream>>>(in_b,   kT,           w_q,  w_q, 2048, 1 << 30);
  gemm_mfma<1><<<dim3(16, 32), blk, 0, stream>>>(full_b, kT + 1048576, w_k,  w_v, 4096, 1024);
  gemm_mfma<1><<<dim3(8, 33),  blk, 0, stream>>>(rel_b,  kT + 3145728, w_rh, w_rh, 4098, 1 << 30);
  seg_proj<<<128, blk, 0, stream>>>(w_q, bias_s, seg_embed, qs);

  // fused attention
  attn_mfma<<<dim3(16, 16, 2), blk, 0, stream>>>(w_q, w_k, w_v, w_rh, qs, seg_mat, perm,
                                                 bias_c, bias_r, a_hi, a_lo);

  // output projection (hi + lo for accuracy)
  gemm_mfma<0><<<dim3(8, 16), blk, 0, stream>>>(a_hi, kT + 4194304, out, out, 2048, 1 << 30);
  gemm_mfma<2><<<dim3(8, 16), blk, 0, stream>>>(a_lo, kT + 4194304, out, out, 2048, 1 << 30);
}

// Round 3
// 323.245 us; speedup vs baseline: 6.2197x; 1.0077x over previous
//
#include <hip/hip_runtime.h>

typedef __bf16 bf16;
typedef unsigned short u16;
typedef unsigned int u32;
typedef __attribute__((ext_vector_type(8))) __bf16 bf16x8;
typedef __attribute__((ext_vector_type(4))) __bf16 bf16x4;
typedef __attribute__((ext_vector_type(4))) float f32x4;
typedef __attribute__((ext_vector_type(8))) float f32x8;

// slot index (16B units) for 8-seg rows (64 bf16/row), XOR-swizzled
#define SWZ(r, s) (((r) << 3) + ((s) ^ ((r) & 7)))
// slot index for 4-seg rows (32 bf16/row), XOR-swizzled
#define GSW(r, s) (((r) << 2) + ((s) ^ (((r) >> 1) & 3)))

__device__ __forceinline__ f32x4 mfma16(bf16x8 a, bf16x8 b, f32x4 c) {
  return __builtin_amdgcn_mfma_f32_16x16x32_bf16(a, b, c, 0, 0, 0);
}
__device__ __forceinline__ void gld16(const void* g, void* l) {
  __builtin_amdgcn_global_load_lds((const __attribute__((address_space(1))) void*)g,
                                   (__attribute__((address_space(3))) void*)l, 16, 0, 0);
}

// ---------------------------------------------------------------------------
// prep kernels
// ---------------------------------------------------------------------------
__global__ __launch_bounds__(256) void cvt_bf16(const float* __restrict__ s,
                                                bf16* __restrict__ d, int n) {
  int i = (blockIdx.x * 256 + threadIdx.x) * 4;
  if (i < n) {
    f32x4 v = *reinterpret_cast<const f32x4*>(s + i);
    *reinterpret_cast<bf16x4*>(d + i) = __builtin_convertvector(v, bf16x4);
  }
}

__global__ __launch_bounds__(256) void cvt_full(const float* __restrict__ mem,
                                                const float* __restrict__ cont,
                                                bf16* __restrict__ d) {
  size_t i = ((size_t)blockIdx.x * 256 + threadIdx.x) * 4;
  int row = (int)(i >> 10), col = (int)(i & 1023);
  int b = row >> 11, r = row & 2047;
  const float* src = (r < 1024)
      ? (mem  + (((size_t)(b << 10) + r)        << 10) + col)
      : (cont + (((size_t)(b << 10) + (r - 1024)) << 10) + col);
  f32x4 v = *reinterpret_cast<const f32x4*>(src);
  *reinterpret_cast<bf16x4*>(d + i) = __builtin_convertvector(v, bf16x4);
}

__global__ __launch_bounds__(256) void kT_cvt(const float* __restrict__ K,
                                              bf16* __restrict__ KT) {
  __shared__ float t[64][68];
  const int n0 = blockIdx.x << 6, k0 = blockIdx.y << 6;
  for (int idx = threadIdx.x; idx < 1024; idx += 256) {
    int r = idx >> 4, c4 = (idx & 15) << 2;
    f32x4 v = *reinterpret_cast<const f32x4*>(K + (size_t)(k0 + r) * 5120 + n0 + c4);
    t[r][c4] = v.x; t[r][c4 + 1] = v.y; t[r][c4 + 2] = v.z; t[r][c4 + 3] = v.w;
  }
  __syncthreads();
  for (int idx = threadIdx.x; idx < 1024; idx += 256) {
    int r = idx >> 4, c4 = (idx & 15) << 2;
    bf16x4 o = { (bf16)t[c4][r], (bf16)t[c4 + 1][r], (bf16)t[c4 + 2][r], (bf16)t[c4 + 3][r] };
    *reinterpret_cast<bf16x4*>(KT + (size_t)(n0 + r) * 1024 + k0 + c4) = o;
  }
}

__global__ __launch_bounds__(256) void seg_proj(const bf16* __restrict__ w_q,
                                                const float* __restrict__ bias_s,
                                                const float* __restrict__ seg_embed,
                                                float* __restrict__ qs) {
  int idx = blockIdx.x * 256 + threadIdx.x;
  int q = idx & 1023, h = (idx >> 10) & 15, b = idx >> 14;
  const bf16* wp = w_q + (((size_t)(b << 10) + q) << 10) + (h << 6);
  const float* bp = bias_s + (h << 6);
  const float* e0 = seg_embed + (h << 6);
  const float* e1 = seg_embed + 1024 + (h << 6);
  float s0 = 0.f, s1 = 0.f;
#pragma unroll 8
  for (int d = 0; d < 64; ++d) {
    float v = (float)wp[d] + bp[d];
    s0 = fmaf(v, e0[d], s0);
    s1 = fmaf(v, e1[d], s1);
  }
  qs[((size_t)idx << 1) + 0] = s0;
  qs[((size_t)idx << 1) + 1] = s1;
}

// ---------------------------------------------------------------------------
// MFMA GEMM (unchanged from round 2)
// ---------------------------------------------------------------------------
template<int OUT_MODE>
__global__ __launch_bounds__(256) void gemm_mfma(const bf16* __restrict__ A,
                                                 const bf16* __restrict__ BT,
                                                 void* __restrict__ C0v,
                                                 void* __restrict__ C1v,
                                                 int Mrows, int splitN) {
  __shared__ bf16 As[4096];
  __shared__ bf16 Bs[4096];
  const int tid = threadIdx.x;
  const int m0 = blockIdx.y << 7, n0 = blockIdx.x << 7;
  const int l = tid & 63, w = tid >> 6;
  const int wm = (w >> 1) << 6, wn = (w & 1) << 6;
  const int lc = l & 15, l16 = l >> 4;
  f32x4 acc[4][4] = {};
  const int r0 = tid >> 2, r1 = r0 + 64;
  const int sq = tid & 3;
  const int g0 = (sq ^ ((r0 >> 1) & 3)) << 3;

  for (int k0 = 0; k0 < 1024; k0 += 32) {
    __syncthreads();
    gld16(A  + (size_t)(m0 + r0) * 1024 + k0 + g0, &As[tid << 3]);
    gld16(BT + (size_t)(n0 + r0) * 1024 + k0 + g0, &Bs[tid << 3]);
    gld16(A  + (size_t)(m0 + r1) * 1024 + k0 + g0, &As[(tid + 256) << 3]);
    gld16(BT + (size_t)(n0 + r1) * 1024 + k0 + g0, &Bs[(tid + 256) << 3]);
    __syncthreads();
    bf16x8 af[4], bfv[4];
#pragma unroll
    for (int m = 0; m < 4; ++m)
      af[m] = *reinterpret_cast<const bf16x8*>(&As[GSW(wm + (m << 4) + lc, l16) << 3]);
#pragma unroll
    for (int n = 0; n < 4; ++n)
      bfv[n] = *reinterpret_cast<const bf16x8*>(&Bs[GSW(wn + (n << 4) + lc, l16) << 3]);
#pragma unroll
    for (int m = 0; m < 4; ++m)
#pragma unroll
      for (int n = 0; n < 4; ++n)
        acc[m][n] = mfma16(af[m], bfv[n], acc[m][n]);
  }
#pragma unroll
  for (int m = 0; m < 4; ++m) {
    const int rbase = m0 + wm + (m << 4) + (l16 << 2);
#pragma unroll
    for (int n = 0; n < 4; ++n) {
      const int col = n0 + wn + (n << 4) + lc;
      const int cc = (col < splitN) ? col : (col - splitN);
      void* Cv = (col < splitN) ? C0v : C1v;
#pragma unroll
      for (int r = 0; r < 4; ++r) {
        const int row = rbase + r;
        if (row < Mrows) {
          const float v = acc[m][n][r];
          const size_t off = ((size_t)row << 10) + cc;
          if (OUT_MODE == 1)      ((bf16*)Cv)[off] = (bf16)v;
          else if (OUT_MODE == 0) ((float*)Cv)[off] = v;
          else                    ((float*)Cv)[off] += v;
        }
      }
    }
  }
}

// ---------------------------------------------------------------------------
// fused attention, swapped-QK^T, in-register softmax.
// rel shift: diff=j_g-i_g; diff<=1024 -> q_r[i].w_r[diff+1024]
//            diff>=1025 -> q_r[i+1].w_r[diff-1025]
// band A base = rel0+961, band B base = rel0-1088; per-wave window base 48-w*16;
// needed band-local (per wave) col for (q-local lc, k-local j) = 15 + j - lc.
// ---------------------------------------------------------------------------
__global__ __launch_bounds__(256) void attn_mfma(
    const bf16* __restrict__ w_q, const bf16* __restrict__ w_k,
    const bf16* __restrict__ w_v, const bf16* __restrict__ w_rh,
    const float* __restrict__ qs_seg, const float* __restrict__ seg_mat,
    const float* __restrict__ perm, const float* __restrict__ bias_c,
    const float* __restrict__ bias_r, bf16* __restrict__ a_hi,
    bf16* __restrict__ a_lo) {
  // XCD-aware swizzle: blocks with id%8 == x share (b,qt) seg/perm slices on XCD x
  const int id = blockIdx.x;
  const int h  = (id >> 3) & 15;
  const int cg = (id & 7) | ((id >> 7) << 3);
  const int qt = cg & 15, b = cg >> 4;
  const int qi0 = qt << 6;
  const int tid = threadIdx.x;
  const int w = tid >> 6, l = tid & 63;
  const int lc = l & 15, l16 = l >> 4;
  const int w16 = w << 4;
  const int myq = w16 + lc;        // this lane's q-row (softmax mapping)

  __shared__ bf16 qc[64 * 64];     // swizzled [q][d]
  __shared__ bf16 qr[65 * 64];     // swizzled (+1 row for spill)
  __shared__ bf16 kt[32 * 64];     // swizzled [k][d]
  __shared__ u16  vt[64 * 40];     // V^T [d][k], stride 40
  __shared__ bf16 wb[2 * 96 * 64]; // w_r bands, swizzled
  __shared__ u16  pl[64 * 40];     // P [q][k], stride 40
  __shared__ float ART[4 * 960];   // per-wave [bandcol 0..47][q-local], stride 20
  __shared__ float facw[64], lroww[64];

  // ---- stage q tiles (bias added, back to bf16, swizzled) ----
  for (int c = tid; c < 520; c += 256) {
    int r = c >> 3, s = c & 7;
    int grow = qi0 + r; if (grow > 1023) grow = 1023;
    bf16x8 qv = *reinterpret_cast<const bf16x8*>(
        w_q + (((size_t)(b << 10) + grow) << 10) + (h << 6) + (s << 3));
    f32x8 qf = __builtin_convertvector(qv, f32x8);
    f32x8 brv = *reinterpret_cast<const f32x8*>(bias_r + (h << 6) + (s << 3));
    *reinterpret_cast<bf16x8*>(&qr[SWZ(r, s) << 3]) = __builtin_convertvector(qf + brv, bf16x8);
    if (c < 512) {
      f32x8 bcv = *reinterpret_cast<const f32x8*>(bias_c + (h << 6) + (s << 3));
      *reinterpret_cast<bf16x8*>(&qc[SWZ(r, s) << 3]) = __builtin_convertvector(qf + bcv, bf16x8);
    }
  }

  const float* qp = qs_seg + ((((size_t)((b << 4) + h) << 10) + qi0 + myq) << 1);
  const float qs0 = qp[0], qs1 = qp[1];
  float mrow = -1e30f, lrow = 0.f;
  f32x4 o[4] = {};
  const float SCL = 0.125f * 1.44269504f;   // fold 1/sqrt(DH) and log2(e) -> exp2 domain

  for (int kj = 0; kj < 2048; kj += 32) {
    const int rel0 = kj - qi0;
    const bool strad = (rel0 >= 994) && (rel0 <= 1087);
    const int firstVar = (rel0 >= 1088) ? 1 : 0;
    __syncthreads();  // (a) previous tile fully consumed

    // ---- stage K tile ----
    {
      int r = tid >> 3, s = tid & 7;
      gld16(w_k + ((size_t)((b << 11) + kj + r) << 10) + (h << 6) + ((s ^ (r & 7)) << 3),
            &kt[tid << 3]);
    }
    // ---- stage w_r band(s) ----
    {
      const int cbase = firstVar ? (rel0 - 1088) : (rel0 + 961);
      for (int c = tid; c < 768; c += 256) {
        int r = c >> 3, s = c & 7;
        int grow = cbase + r; grow = grow < 0 ? 0 : (grow > 2048 ? 2048 : grow);
        gld16(w_rh + ((size_t)(b * 2049 + grow) << 10) + (h << 6) + ((s ^ (r & 7)) << 3),
              &wb[c << 3]);
      }
      if (strad) {
        const int cbase2 = rel0 - 1088;
        for (int c = tid; c < 768; c += 256) {
          int r = c >> 3, s = c & 7;
          int grow = cbase2 + r; grow = grow < 0 ? 0 : (grow > 2048 ? 2048 : grow);
          gld16(w_rh + ((size_t)(b * 2049 + grow) << 10) + (h << 6) + ((s ^ (r & 7)) << 3),
                &wb[6144 + (c << 3)]);
        }
      }
    }
    // ---- stage V^T (register transpose; write 2-way conflict-free) ----
    {
      const int kv2 = (tid & 15) << 1, d4 = ((tid >> 4) & 15) << 2;
      const u16* vp = (const u16*)w_v + ((size_t)((b << 11) + kj + kv2) << 10) + (h << 6) + d4;
      uint2 ra = *reinterpret_cast<const uint2*>(vp);
      uint2 rb = *reinterpret_cast<const uint2*>(vp + 1024);
      u32* vt32 = reinterpret_cast<u32*>(&vt[0]);
      const int kw = kv2 >> 1;
      vt32[(d4 + 0) * 20 + kw] = (ra.x & 0xffffu) | (rb.x << 16);
      vt32[(d4 + 1) * 20 + kw] = (ra.x >> 16) | (rb.x & 0xffff0000u);
      vt32[(d4 + 2) * 20 + kw] = (ra.y & 0xffffu) | (rb.y << 16);
      vt32[(d4 + 3) * 20 + kw] = (ra.y >> 16) | (rb.y & 0xffff0000u);
    }
    // ---- per-lane seg/perm prefetch (k groups: A=4*l16.., B=16+4*l16..) ----
    float segA[8], segB[8], pmA[4], pmB[4];
    {
      const size_t qrow = (size_t)((b << 10) + qi0 + myq);
      const float* sp = seg_mat + (qrow * 2048 + kj + (l16 << 2)) * 2;
      *reinterpret_cast<f32x4*>(&segA[0]) = *reinterpret_cast<const f32x4*>(sp);
      *reinterpret_cast<f32x4*>(&segA[4]) = *reinterpret_cast<const f32x4*>(sp + 4);
      *reinterpret_cast<f32x4*>(&segB[0]) = *reinterpret_cast<const f32x4*>(sp + 32);
      *reinterpret_cast<f32x4*>(&segB[4]) = *reinterpret_cast<const f32x4*>(sp + 36);
      const float* pp = perm + qrow * 2048 + kj + (l16 << 2);
      *reinterpret_cast<f32x4*>(&pmA[0]) = *reinterpret_cast<const f32x4*>(pp);
      *reinterpret_cast<f32x4*>(&pmB[0]) = *reinterpret_cast<const f32x4*>(pp + 16);
    }
    __syncthreads();  // (b) tiles ready

    // ---- context scores, swapped: D[k'][q=lc] ----
    f32x4 s0 = {0.f, 0.f, 0.f, 0.f}, s1 = {0.f, 0.f, 0.f, 0.f};
    {
      bf16x8 bq0 = *reinterpret_cast<const bf16x8*>(&qc[SWZ(myq, l16) << 3]);
      bf16x8 bq1 = *reinterpret_cast<const bf16x8*>(&qc[SWZ(myq, l16 + 4) << 3]);
      bf16x8 a0 = *reinterpret_cast<const bf16x8*>(&kt[SWZ(lc, l16) << 3]);
      bf16x8 a1 = *reinterpret_cast<const bf16x8*>(&kt[SWZ(lc, l16 + 4) << 3]);
      s0 = mfma16(a0, bq0, s0); s0 = mfma16(a1, bq1, s0);
      a0 = *reinterpret_cast<const bf16x8*>(&kt[SWZ(16 + lc, l16) << 3]);
      a1 = *reinterpret_cast<const bf16x8*>(&kt[SWZ(16 + lc, l16 + 4) << 3]);
      s1 = mfma16(a0, bq0, s1); s1 = mfma16(a1, bq1, s1);
    }

    // ---- relative term: normal orientation -> ART[bandcol][q], then gather ----
    float relv[8];
    {
      bf16x8 ar0 = *reinterpret_cast<const bf16x8*>(&qr[SWZ(w16 + lc + firstVar, l16) << 3]);
      bf16x8 ar1 = *reinterpret_cast<const bf16x8*>(&qr[SWZ(w16 + lc + firstVar, l16 + 4) << 3]);
#pragma unroll
      for (int bg = 0; bg < 3; ++bg) {
        const int brow = 48 - w16 + (bg << 4) + lc;
        bf16x8 w0 = *reinterpret_cast<const bf16x8*>(&wb[SWZ(brow, l16) << 3]);
        bf16x8 w1 = *reinterpret_cast<const bf16x8*>(&wb[SWZ(brow, l16 + 4) << 3]);
        f32x4 a_ = {0.f, 0.f, 0.f, 0.f};
        a_ = mfma16(ar0, w0, a_); a_ = mfma16(ar1, w1, a_);
        *reinterpret_cast<f32x4*>(&ART[w * 960 + ((bg << 4) + lc) * 20 + (l16 << 2)]) = a_;
      }
#pragma unroll
      for (int jj = 0; jj < 4; ++jj) {
        relv[jj]     = ART[w * 960 + (15 + (l16 << 2) + jj - lc) * 20 + lc];
        relv[4 + jj] = ART[w * 960 + (31 + (l16 << 2) + jj - lc) * 20 + lc];
      }
      if (strad) {
        // variant B pass: q_r[i+1], band B (wb+6144); select per element
        bf16x8 br0 = *reinterpret_cast<const bf16x8*>(&qr[SWZ(w16 + lc + 1, l16) << 3]);
        bf16x8 br1 = *reinterpret_cast<const bf16x8*>(&qr[SWZ(w16 + lc + 1, l16 + 4) << 3]);
#pragma unroll
        for (int bg = 0; bg < 3; ++bg) {
          const int brow = 48 - w16 + (bg << 4) + lc;
          bf16x8 w0 = *reinterpret_cast<const bf16x8*>(&wb[6144 + (SWZ(brow, l16) << 3)]);
          bf16x8 w1 = *reinterpret_cast<const bf16x8*>(&wb[6144 + (SWZ(brow, l16 + 4) << 3)]);
          f32x4 a_ = {0.f, 0.f, 0.f, 0.f};
          a_ = mfma16(br0, w0, a_); a_ = mfma16(br1, w1, a_);
          *reinterpret_cast<f32x4*>(&ART[w * 960 + ((bg << 4) + lc) * 20 + (l16 << 2)]) = a_;
        }
#pragma unroll
        for (int jj = 0; jj < 4; ++jj) {
          const int jA = (l16 << 2) + jj, jB = 16 + (l16 << 2) + jj;
          float rbA = ART[w * 960 + (15 + jA - lc) * 20 + lc];
          float rbB = ART[w * 960 + (15 + jB - lc) * 20 + lc];
          if (rel0 + jA - myq >= 1025) relv[jj] = rbA;
          if (rel0 + jB - myq >= 1025) relv[4 + jj] = rbB;
        }
      }
    }

    // ---- in-register online softmax (q = myq, 8 k-values per lane) ----
    {
      float sv[8];
#pragma unroll
      for (int jj = 0; jj < 4; ++jj) {
        sv[jj]     = (s0[jj] + relv[jj]     + segA[2 * jj] * qs0 + segA[2 * jj + 1] * qs1) * SCL;
        sv[4 + jj] = (s1[jj] + relv[4 + jj] + segB[2 * jj] * qs0 + segB[2 * jj + 1] * qs1) * SCL;
      }
      float tm = sv[0];
#pragma unroll
      for (int jj = 1; jj < 8; ++jj) tm = fmaxf(tm, sv[jj]);
      tm = fmaxf(tm, __shfl_xor(tm, 16));
      tm = fmaxf(tm, __shfl_xor(tm, 32));
      const float mn2 = fmaxf(mrow, tm);
      const float facr = exp2f(mrow - mn2);
      float e[8], rs = 0.f;
#pragma unroll
      for (int jj = 0; jj < 4; ++jj) {
        e[jj]     = exp2f(sv[jj] - mn2) * pmA[jj];
        e[4 + jj] = exp2f(sv[4 + jj] - mn2) * pmB[jj];
        rs += e[jj] + e[4 + jj];
      }
      rs += __shfl_xor(rs, 16);
      rs += __shfl_xor(rs, 32);
      mrow = mn2;
      lrow = lrow * facr + rs;
      bf16x4 pa, pb;
#pragma unroll
      for (int jj = 0; jj < 4; ++jj) { pa[jj] = (bf16)e[jj]; pb[jj] = (bf16)e[4 + jj]; }
      *reinterpret_cast<bf16x4*>(&pl[myq * 40 + (l16 << 2)]) = pa;
      *reinterpret_cast<bf16x4*>(&pl[myq * 40 + 16 + (l16 << 2)]) = pb;
      if (l16 == 0) facw[myq] = facr;
    }

    // ---- PV (wave-private pl/facw, no barrier needed) ----
    {
      float fr[4];
#pragma unroll
      for (int r = 0; r < 4; ++r) fr[r] = facw[w16 + (l16 << 2) + r];
#pragma unroll
      for (int n = 0; n < 4; ++n)
#pragma unroll
        for (int r = 0; r < 4; ++r) o[n][r] *= fr[r];
      bf16x8 ap = *reinterpret_cast<const bf16x8*>(&pl[(w16 + lc) * 40 + (l16 << 3)]);
#pragma unroll
      for (int n = 0; n < 4; ++n) {
        bf16x8 bv = *reinterpret_cast<const bf16x8*>(&vt[((n << 4) + lc) * 40 + (l16 << 3)]);
        o[n] = mfma16(ap, bv, o[n]);
      }
    }
  }

  // ---- epilogue ----
  if (l16 == 0) lroww[myq] = lrow;
  {
    float inv[4];
#pragma unroll
    for (int r = 0; r < 4; ++r)
      inv[r] = 1.f / (lroww[w16 + (l16 << 2) + r] + 1e-7f);
#pragma unroll
    for (int n = 0; n < 4; ++n) {
#pragma unroll
      for (int r = 0; r < 4; ++r) {
        const int row = qi0 + w16 + (l16 << 2) + r;
        const float v = o[n][r] * inv[r];
        const bf16 hi = (bf16)v;
        const float lof = v - (float)hi;
        const size_t off = (((size_t)(b << 10) + row) << 10) + (h << 6) + (n << 4) + lc;
        a_hi[off] = hi;
        a_lo[off] = (bf16)lof;
      }
    }
  }
}

// ---------------------------------------------------------------------------
extern "C" void kernel_launch(void* const* d_in, const int* in_sizes, int n_in,
                              void* d_out, int out_size, void* d_ws, size_t ws_size,
                              hipStream_t stream) {
  (void)in_sizes; (void)n_in; (void)out_size; (void)ws_size;
  const float* inputs    = (const float*)d_in[0];
  const float* content   = (const float*)d_in[1];
  const float* memories  = (const float*)d_in[2];
  const float* relatives = (const float*)d_in[3];
  const float* seg_mat   = (const float*)d_in[4];
  const float* seg_embed = (const float*)d_in[5];
  const float* bias_c    = (const float*)d_in[6];
  const float* bias_r    = (const float*)d_in[7];
  const float* bias_s    = (const float*)d_in[8];
  const float* perm      = (const float*)d_in[9];
  const float* kern      = (const float*)d_in[10];
  float* out = (float*)d_out;

  char* ws = (char*)d_ws;
  bf16*  in_b   = (bf16*)(ws);
  bf16*  full_b = (bf16*)(ws + 4194304);
  bf16*  rel_b  = (bf16*)(ws + 12582912);
  bf16*  kT     = (bf16*)(ws + 21233664);
  bf16*  w_q    = (bf16*)(ws + 31719424);
  bf16*  w_k    = (bf16*)(ws + 35913728);
  bf16*  w_v    = (bf16*)(ws + 44302336);
  bf16*  w_rh   = (bf16*)(ws + 52690944);
  bf16*  a_hi   = (bf16*)(ws + 61083648);
  float* qs     = (float*)(ws + 65277952);
  bf16*  a_lo   = in_b;  // reuse

  dim3 blk(256);
  cvt_bf16<<<2048, blk, 0, stream>>>(inputs, in_b, 2097152);
  cvt_full<<<4096, blk, 0, stream>>>(memories, content, full_b);
  cvt_bf16<<<4098, blk, 0, stream>>>(relatives, rel_b, 4196352);
  kT_cvt<<<dim3(80, 16), blk, 0, stream>>>(kern, kT);

  gemm_mfma<1><<<dim3(8, 16),  blk, 0, stream>>>(in_b,   kT,           w_q,  w_q, 2048, 1 << 30);
  gemm_mfma<1><<<dim3(16, 32), blk, 0, stream>>>(full_b, kT + 1048576, w_k,  w_v, 4096, 1024);
  gemm_mfma<1><<<dim3(8, 33),  blk, 0, stream>>>(rel_b,  kT + 3145728, w_rh, w_rh, 4098, 1 << 30);
  seg_proj<<<128, blk, 0, stream>>>(w_q, bias_s, seg_embed, qs);

  attn_mfma<<<512, blk, 0, stream>>>(w_q, w_k, w_v, w_rh, qs, seg_mat, perm,
                                     bias_c, bias_r, a_hi, a_lo);

  gemm_mfma<0><<<dim3(8, 16), blk, 0, stream>>>(a_hi, kT + 4194304, out, out, 2048, 1 << 30);
  gemm_mfma<2><<<dim3(8, 16), blk, 0, stream>>>(a_lo, kT + 4194304, out, out, 2048, 1 << 30);
}

// Round 4
// 297.865 us; speedup vs baseline: 6.7497x; 1.0852x over previous
//
#include <hip/hip_runtime.h>

typedef __bf16 bf16;
typedef unsigned short u16;
typedef unsigned int u32;
typedef __attribute__((ext_vector_type(8))) __bf16 bf16x8;
typedef __attribute__((ext_vector_type(4))) __bf16 bf16x4;
typedef __attribute__((ext_vector_type(4))) float f32x4;
typedef __attribute__((ext_vector_type(8))) float f32x8;

// slot index (16B units) for 8-seg rows (64 bf16/row), XOR-swizzled
#define SWZ(r, s) (((r) << 3) + ((s) ^ ((r) & 7)))
// slot index for 4-seg rows (32 bf16/row), XOR-swizzled
#define GSW(r, s) (((r) << 2) + ((s) ^ (((r) >> 1) & 3)))

__device__ __forceinline__ f32x4 mfma16(bf16x8 a, bf16x8 b, f32x4 c) {
  return __builtin_amdgcn_mfma_f32_16x16x32_bf16(a, b, c, 0, 0, 0);
}
__device__ __forceinline__ void gld16(const void* g, void* l) {
  __builtin_amdgcn_global_load_lds((const __attribute__((address_space(1))) void*)g,
                                   (__attribute__((address_space(3))) void*)l, 16, 0, 0);
}

// ---------------------------------------------------------------------------
// prep kernels
// ---------------------------------------------------------------------------
__global__ __launch_bounds__(256) void cvt_bf16(const float* __restrict__ s,
                                                bf16* __restrict__ d, int n) {
  int i = (blockIdx.x * 256 + threadIdx.x) * 4;
  if (i < n) {
    f32x4 v = *reinterpret_cast<const f32x4*>(s + i);
    *reinterpret_cast<bf16x4*>(d + i) = __builtin_convertvector(v, bf16x4);
  }
}

__global__ __launch_bounds__(256) void cvt_full(const float* __restrict__ mem,
                                                const float* __restrict__ cont,
                                                bf16* __restrict__ d) {
  size_t i = ((size_t)blockIdx.x * 256 + threadIdx.x) * 4;
  int row = (int)(i >> 10), col = (int)(i & 1023);
  int b = row >> 11, r = row & 2047;
  const float* src = (r < 1024)
      ? (mem  + (((size_t)(b << 10) + r)        << 10) + col)
      : (cont + (((size_t)(b << 10) + (r - 1024)) << 10) + col);
  f32x4 v = *reinterpret_cast<const f32x4*>(src);
  *reinterpret_cast<bf16x4*>(d + i) = __builtin_convertvector(v, bf16x4);
}

// seg_mat f32 -> bf16 (8,388,608 elements)
__global__ __launch_bounds__(256) void cvt_seg(const float* __restrict__ s,
                                               bf16* __restrict__ d) {
  size_t i = ((size_t)blockIdx.x * 256 + threadIdx.x) * 8;
  f32x8 v = *reinterpret_cast<const f32x8*>(s + i);
  *reinterpret_cast<bf16x8*>(d + i) = __builtin_convertvector(v, bf16x8);
}

__global__ __launch_bounds__(256) void kT_cvt(const float* __restrict__ K,
                                              bf16* __restrict__ KT) {
  __shared__ float t[64][68];
  const int n0 = blockIdx.x << 6, k0 = blockIdx.y << 6;
  for (int idx = threadIdx.x; idx < 1024; idx += 256) {
    int r = idx >> 4, c4 = (idx & 15) << 2;
    f32x4 v = *reinterpret_cast<const f32x4*>(K + (size_t)(k0 + r) * 5120 + n0 + c4);
    t[r][c4] = v.x; t[r][c4 + 1] = v.y; t[r][c4 + 2] = v.z; t[r][c4 + 3] = v.w;
  }
  __syncthreads();
  for (int idx = threadIdx.x; idx < 1024; idx += 256) {
    int r = idx >> 4, c4 = (idx & 15) << 2;
    bf16x4 o = { (bf16)t[c4][r], (bf16)t[c4 + 1][r], (bf16)t[c4 + 2][r], (bf16)t[c4 + 3][r] };
    *reinterpret_cast<bf16x4*>(KT + (size_t)(n0 + r) * 1024 + k0 + c4) = o;
  }
}

__global__ __launch_bounds__(256) void seg_proj(const bf16* __restrict__ w_q,
                                                const float* __restrict__ bias_s,
                                                const float* __restrict__ seg_embed,
                                                float* __restrict__ qs) {
  int idx = blockIdx.x * 256 + threadIdx.x;
  int q = idx & 1023, h = (idx >> 10) & 15, b = idx >> 14;
  const bf16* wp = w_q + (((size_t)(b << 10) + q) << 10) + (h << 6);
  const float* bp = bias_s + (h << 6);
  const float* e0 = seg_embed + (h << 6);
  const float* e1 = seg_embed + 1024 + (h << 6);
  float s0 = 0.f, s1 = 0.f;
#pragma unroll 8
  for (int d = 0; d < 64; ++d) {
    float v = (float)wp[d] + bp[d];
    s0 = fmaf(v, e0[d], s0);
    s1 = fmaf(v, e1[d], s1);
  }
  qs[((size_t)idx << 1) + 0] = s0;
  qs[((size_t)idx << 1) + 1] = s1;
}

// ---------------------------------------------------------------------------
// MFMA GEMM (unchanged from round 2)
// ---------------------------------------------------------------------------
template<int OUT_MODE>
__global__ __launch_bounds__(256) void gemm_mfma(const bf16* __restrict__ A,
                                                 const bf16* __restrict__ BT,
                                                 void* __restrict__ C0v,
                                                 void* __restrict__ C1v,
                                                 int Mrows, int splitN) {
  __shared__ bf16 As[4096];
  __shared__ bf16 Bs[4096];
  const int tid = threadIdx.x;
  const int m0 = blockIdx.y << 7, n0 = blockIdx.x << 7;
  const int l = tid & 63, w = tid >> 6;
  const int wm = (w >> 1) << 6, wn = (w & 1) << 6;
  const int lc = l & 15, l16 = l >> 4;
  f32x4 acc[4][4] = {};
  const int r0 = tid >> 2, r1 = r0 + 64;
  const int sq = tid & 3;
  const int g0 = (sq ^ ((r0 >> 1) & 3)) << 3;

  for (int k0 = 0; k0 < 1024; k0 += 32) {
    __syncthreads();
    gld16(A  + (size_t)(m0 + r0) * 1024 + k0 + g0, &As[tid << 3]);
    gld16(BT + (size_t)(n0 + r0) * 1024 + k0 + g0, &Bs[tid << 3]);
    gld16(A  + (size_t)(m0 + r1) * 1024 + k0 + g0, &As[(tid + 256) << 3]);
    gld16(BT + (size_t)(n0 + r1) * 1024 + k0 + g0, &Bs[(tid + 256) << 3]);
    __syncthreads();
    bf16x8 af[4], bfv[4];
#pragma unroll
    for (int m = 0; m < 4; ++m)
      af[m] = *reinterpret_cast<const bf16x8*>(&As[GSW(wm + (m << 4) + lc, l16) << 3]);
#pragma unroll
    for (int n = 0; n < 4; ++n)
      bfv[n] = *reinterpret_cast<const bf16x8*>(&Bs[GSW(wn + (n << 4) + lc, l16) << 3]);
#pragma unroll
    for (int m = 0; m < 4; ++m)
#pragma unroll
      for (int n = 0; n < 4; ++n)
        acc[m][n] = mfma16(af[m], bfv[n], acc[m][n]);
  }
#pragma unroll
  for (int m = 0; m < 4; ++m) {
    const int rbase = m0 + wm + (m << 4) + (l16 << 2);
#pragma unroll
    for (int n = 0; n < 4; ++n) {
      const int col = n0 + wn + (n << 4) + lc;
      const int cc = (col < splitN) ? col : (col - splitN);
      void* Cv = (col < splitN) ? C0v : C1v;
#pragma unroll
      for (int r = 0; r < 4; ++r) {
        const int row = rbase + r;
        if (row < Mrows) {
          const float v = acc[m][n][r];
          const size_t off = ((size_t)row << 10) + cc;
          if (OUT_MODE == 1)      ((bf16*)Cv)[off] = (bf16)v;
          else if (OUT_MODE == 0) ((float*)Cv)[off] = v;
          else                    ((float*)Cv)[off] += v;
        }
      }
    }
  }
}

// ---------------------------------------------------------------------------
// fused attention: 2-phase double-buffered pipeline, Q in registers,
// rolling circular w_r band.
// rel shift: diff=j_g-i_g; diff<=1024 -> q_r[i].w_r[diff+1024]
//            diff>=1025 -> q_r[i+1].w_r[diff-1025]
// Variant A band row L = diff+1024, staged window [rel0+961, rel0+1056].
// Variant B band row L = diff-1025 (w_r row directly).
// Circular: slot = (L+OFF)&127, OFF_A=7, OFF_B=0 (keeps appends 8-row aligned
// so gld16 dest is wave-linear). Strad steps rel0 in {1024,1056} + switch step
// rel0==1088 use wb2[96] indexed by w_r row 0..95 directly.
// ---------------------------------------------------------------------------
#define OFFA 7
#define OFFB 0

__global__ __launch_bounds__(256) void attn_mfma(
    const bf16* __restrict__ w_q, const bf16* __restrict__ w_k,
    const bf16* __restrict__ w_v, const bf16* __restrict__ w_rh,
    const float* __restrict__ qs_seg, const bf16* __restrict__ seg_b,
    const float* __restrict__ perm, const float* __restrict__ bias_c,
    const float* __restrict__ bias_r, bf16* __restrict__ a_hi,
    bf16* __restrict__ a_lo) {
  const int id = blockIdx.x;
  const int h  = (id >> 3) & 15;
  const int cg = (id & 7) | ((id >> 7) << 3);
  const int qt = cg & 15, b = cg >> 4;
  const int qi0 = qt << 6;
  const int tid = threadIdx.x;
  const int w = tid >> 6, l = tid & 63;
  const int lc = l & 15, l16 = l >> 4;
  const int w16 = w << 4;
  const int myq = w16 + lc;

  __shared__ bf16 kt[2][32 * 64];   // 8 KB  (swizzled)
  __shared__ u16  vt[2][64 * 40];   // 10 KB (V^T stride 40)
  __shared__ bf16 wbc[128 * 64];    // 16 KB circular band (swizzled by slot)
  __shared__ bf16 wb2[96 * 64];     // 12 KB band-B rows 0..95 (swizzled)
  __shared__ u16  pl[64 * 40];      // 5 KB
  __shared__ float ART[4 * 960];    // 15.36 KB per-wave gather scratch
  __shared__ float facw[64], lroww[64];

  // ---- staging helpers ----
  auto stageK = [&](int buf, int kj) {
    int r = tid >> 3, s = tid & 7;
    gld16(w_k + ((size_t)((b << 11) + kj + r) << 10) + (h << 6) + ((s ^ (r & 7)) << 3),
          &kt[buf][tid << 3]);
  };
  auto stageWB = [&](int L0, int nrows, int OFF) {
    for (int base = 0; base < nrows; base += 32) {
      int r = (tid >> 3) + base, s = tid & 7;
      int L = L0 + r;
      int slot = (L + OFF) & 127;
      int grow = L > 2048 ? 2048 : L;
      gld16(w_rh + ((size_t)(b * 2049 + grow) << 10) + (h << 6) + ((s ^ (slot & 7)) << 3),
            &wbc[((slot << 3) | s) << 3]);
    }
  };
  auto stageWB2 = [&]() {
    for (int base = 0; base < 96; base += 32) {
      int r = (tid >> 3) + base, s = tid & 7;
      gld16(w_rh + ((size_t)(b * 2049 + r) << 10) + (h << 6) + ((s ^ (r & 7)) << 3),
            &wb2[((r << 3) | s) << 3]);
    }
  };
  const int kv2 = (tid & 15) << 1, d4 = ((tid >> 4) & 15) << 2, kw = tid & 15;
  auto loadV = [&](int kj, uint2& ra, uint2& rb) {
    const u16* vp = (const u16*)w_v + ((size_t)((b << 11) + kj + kv2) << 10) + (h << 6) + d4;
    ra = *reinterpret_cast<const uint2*>(vp);
    rb = *reinterpret_cast<const uint2*>(vp + 1024);
  };
  auto writeV = [&](int buf, uint2 ra, uint2 rb) {
    u32* vt32 = reinterpret_cast<u32*>(&vt[buf][0]);
    vt32[(d4 + 0) * 20 + kw] = (ra.x & 0xffffu) | (rb.x << 16);
    vt32[(d4 + 1) * 20 + kw] = (ra.x >> 16) | (rb.x & 0xffff0000u);
    vt32[(d4 + 2) * 20 + kw] = (ra.y & 0xffffu) | (rb.y << 16);
    vt32[(d4 + 3) * 20 + kw] = (ra.y >> 16) | (rb.y & 0xffff0000u);
  };
  const size_t qrowg = (size_t)((b << 10) + qi0 + myq);
  auto loadSP = [&](int kj, bf16x8& sA, bf16x8& sB, f32x4& pA, f32x4& pB) {
    const bf16* sp = seg_b + (qrowg * 2048 + kj + (l16 << 2)) * 2;
    sA = *reinterpret_cast<const bf16x8*>(sp);
    sB = *reinterpret_cast<const bf16x8*>(sp + 32);
    const float* pp = perm + qrowg * 2048 + kj + (l16 << 2);
    pA = *reinterpret_cast<const f32x4*>(pp);
    pB = *reinterpret_cast<const f32x4*>(pp + 16);
  };

  // ---- prologue: stage tile 0, hoist Q fragments ----
  stageK(0, 0);
  stageWB(961 - qi0, 96, OFFA);   // (961-qi0+7) % 8 == 0
  uint2 ra0, rb0;
  loadV(0, ra0, rb0);
  bf16x8 segA_c, segB_c, segA_n = {}, segB_n = {};
  f32x4 pmA_c, pmB_c, pmA_n = {}, pmB_n = {};
  loadSP(0, segA_c, segB_c, pmA_c, pmB_c);

  const int dlo = l16 << 3;
  bf16x8 qcf0, qcf1, qrf0, qrf1, qrg0, qrg1;
  {
    const bf16* qb  = w_q + ((qrowg) << 10) + (h << 6);
    const int rq1 = (qi0 + myq + 1 > 1023) ? 1023 : qi0 + myq + 1;
    const bf16* qb1 = w_q + (((size_t)(b << 10) + rq1) << 10) + (h << 6);
    f32x8 bc0 = *reinterpret_cast<const f32x8*>(bias_c + (h << 6) + dlo);
    f32x8 bc1 = *reinterpret_cast<const f32x8*>(bias_c + (h << 6) + 32 + dlo);
    f32x8 br0 = *reinterpret_cast<const f32x8*>(bias_r + (h << 6) + dlo);
    f32x8 br1 = *reinterpret_cast<const f32x8*>(bias_r + (h << 6) + 32 + dlo);
    bf16x8 q0 = *reinterpret_cast<const bf16x8*>(qb + dlo);
    bf16x8 q1 = *reinterpret_cast<const bf16x8*>(qb + 32 + dlo);
    bf16x8 p0 = *reinterpret_cast<const bf16x8*>(qb1 + dlo);
    bf16x8 p1 = *reinterpret_cast<const bf16x8*>(qb1 + 32 + dlo);
    qcf0 = __builtin_convertvector(__builtin_convertvector(q0, f32x8) + bc0, bf16x8);
    qcf1 = __builtin_convertvector(__builtin_convertvector(q1, f32x8) + bc1, bf16x8);
    qrf0 = __builtin_convertvector(__builtin_convertvector(q0, f32x8) + br0, bf16x8);
    qrf1 = __builtin_convertvector(__builtin_convertvector(q1, f32x8) + br1, bf16x8);
    qrg0 = __builtin_convertvector(__builtin_convertvector(p0, f32x8) + br0, bf16x8);
    qrg1 = __builtin_convertvector(__builtin_convertvector(p1, f32x8) + br1, bf16x8);
  }
  const float* qp = qs_seg + ((((size_t)((b << 4) + h) << 10) + qi0 + myq) << 1);
  const float qs0 = qp[0], qs1 = qp[1];

  writeV(0, ra0, rb0);
  __syncthreads();  // prologue drain

  float mrow = -1e30f, lrow = 0.f;
  f32x4 o[4] = {};
  const float SCL = 0.125f * 1.44269504f;
  int cur = 0;
  uint2 ra_n = {}, rb_n = {};

  for (int t = 0; t < 64; ++t) {
    const int kj = t << 5;
    const int rel0 = kj - qi0;
    const bool strad = (rel0 == 1024) | (rel0 == 1056);
    const bool mainB = (rel0 >= 1088);
    const int nxt = cur ^ 1;

    // ---- STAGE t+1 ----
    if (t < 63) {
      const int kjn = kj + 32, rel0n = rel0 + 32;
      stageK(nxt, kjn);
      if (rel0n == 1024) stageWB2();
      if (rel0n == 1120)      stageWB(32, 96, OFFB);
      else if (rel0n != 1088) {
        if (rel0n <= 1056) stageWB(rel0n + 1025, 32, OFFA);
        else               stageWB(rel0n - 1024, 32, OFFB);
      }
      loadV(kjn, ra_n, rb_n);
      loadSP(kjn, segA_n, segB_n, pmA_n, pmB_n);
    }

    // ---- COMPUTE t ----
    // context scores (swapped): D[k'][q=lc]
    f32x4 s0 = {0.f, 0.f, 0.f, 0.f}, s1 = {0.f, 0.f, 0.f, 0.f};
    {
      const bf16* ktc = kt[cur];
      bf16x8 a0 = *reinterpret_cast<const bf16x8*>(&ktc[SWZ(lc, l16) << 3]);
      bf16x8 a1 = *reinterpret_cast<const bf16x8*>(&ktc[SWZ(lc, l16 + 4) << 3]);
      s0 = mfma16(a0, qcf0, s0); s0 = mfma16(a1, qcf1, s0);
      a0 = *reinterpret_cast<const bf16x8*>(&ktc[SWZ(16 + lc, l16) << 3]);
      a1 = *reinterpret_cast<const bf16x8*>(&ktc[SWZ(16 + lc, l16 + 4) << 3]);
      s1 = mfma16(a0, qcf0, s1); s1 = mfma16(a1, qcf1, s1);
    }

    // relative term via ART[bandcol][q] + diagonal gather
    float relv[8];
    {
      const bf16x8 ar0 = mainB ? qrg0 : qrf0;
      const bf16x8 ar1 = mainB ? qrg1 : qrf1;
      const bool useWb2 = (rel0 == 1088);
      int sbase;
      if (!mainB)       sbase = (rel0 + 1016 - w16) & 127;   // A: OFF=7
      else if (useWb2)  sbase = 48 - w16;                    // B rows directly
      else              sbase = (rel0 - 1040 - w16) & 127;   // B: OFF=0
      const bf16* wbp = useWb2 ? wb2 : wbc;
#pragma unroll
      for (int bg = 0; bg < 3; ++bg) {
        int prow = sbase + (bg << 4) + lc;
        if (!useWb2) prow &= 127;
        bf16x8 w0 = *reinterpret_cast<const bf16x8*>(&wbp[SWZ(prow, l16) << 3]);
        bf16x8 w1 = *reinterpret_cast<const bf16x8*>(&wbp[SWZ(prow, l16 + 4) << 3]);
        f32x4 a_ = {0.f, 0.f, 0.f, 0.f};
        a_ = mfma16(ar0, w0, a_); a_ = mfma16(ar1, w1, a_);
        *reinterpret_cast<f32x4*>(&ART[w * 960 + ((bg << 4) + lc) * 20 + (l16 << 2)]) = a_;
      }
#pragma unroll
      for (int jj = 0; jj < 4; ++jj) {
        relv[jj]     = ART[w * 960 + (15 + (l16 << 2) + jj - lc) * 20 + lc];
        relv[4 + jj] = ART[w * 960 + (31 + (l16 << 2) + jj - lc) * 20 + lc];
      }
      if (strad) {
        // variant-B overlay from wb2 (w_r rows = diff-1025 directly)
#pragma unroll
        for (int bg = 0; bg < 3; ++bg) {
          int srow = rel0 - 1040 - w16 + (bg << 4) + lc;
          srow = srow < 0 ? 0 : (srow > 95 ? 95 : srow);
          bf16x8 w0 = *reinterpret_cast<const bf16x8*>(&wb2[SWZ(srow, l16) << 3]);
          bf16x8 w1 = *reinterpret_cast<const bf16x8*>(&wb2[SWZ(srow, l16 + 4) << 3]);
          f32x4 a_ = {0.f, 0.f, 0.f, 0.f};
          a_ = mfma16(qrg0, w0, a_); a_ = mfma16(qrg1, w1, a_);
          *reinterpret_cast<f32x4*>(&ART[w * 960 + ((bg << 4) + lc) * 20 + (l16 << 2)]) = a_;
        }
#pragma unroll
        for (int jj = 0; jj < 4; ++jj) {
          const int jA = (l16 << 2) + jj, jB = 16 + jA;
          float rbA = ART[w * 960 + (15 + jA - lc) * 20 + lc];
          float rbB = ART[w * 960 + (15 + jB - lc) * 20 + lc];
          if (rel0 + jA - myq >= 1025) relv[jj] = rbA;
          if (rel0 + jB - myq >= 1025) relv[4 + jj] = rbB;
        }
      }
    }

    // in-register online softmax
    {
      f32x8 sgA = __builtin_convertvector(segA_c, f32x8);
      f32x8 sgB = __builtin_convertvector(segB_c, f32x8);
      float sv[8];
#pragma unroll
      for (int jj = 0; jj < 4; ++jj) {
        sv[jj]     = (s0[jj] + relv[jj]     + sgA[2 * jj] * qs0 + sgA[2 * jj + 1] * qs1) * SCL;
        sv[4 + jj] = (s1[jj] + relv[4 + jj] + sgB[2 * jj] * qs0 + sgB[2 * jj + 1] * qs1) * SCL;
      }
      float tm = sv[0];
#pragma unroll
      for (int jj = 1; jj < 8; ++jj) tm = fmaxf(tm, sv[jj]);
      tm = fmaxf(tm, __shfl_xor(tm, 16));
      tm = fmaxf(tm, __shfl_xor(tm, 32));
      const float mn2 = fmaxf(mrow, tm);
      const float facr = exp2f(mrow - mn2);
      float e[8], rs = 0.f;
#pragma unroll
      for (int jj = 0; jj < 4; ++jj) {
        e[jj]     = exp2f(sv[jj] - mn2) * pmA_c[jj];
        e[4 + jj] = exp2f(sv[4 + jj] - mn2) * pmB_c[jj];
        rs += e[jj] + e[4 + jj];
      }
      rs += __shfl_xor(rs, 16);
      rs += __shfl_xor(rs, 32);
      mrow = mn2;
      lrow = lrow * facr + rs;
      bf16x4 pa, pb;
#pragma unroll
      for (int jj = 0; jj < 4; ++jj) { pa[jj] = (bf16)e[jj]; pb[jj] = (bf16)e[4 + jj]; }
      *reinterpret_cast<bf16x4*>(&pl[myq * 40 + (l16 << 2)]) = pa;
      *reinterpret_cast<bf16x4*>(&pl[myq * 40 + 16 + (l16 << 2)]) = pb;
      if (l16 == 0) facw[myq] = facr;
    }

    // PV (wave-private pl/facw)
    {
      float fr[4];
#pragma unroll
      for (int r = 0; r < 4; ++r) fr[r] = facw[w16 + (l16 << 2) + r];
#pragma unroll
      for (int n = 0; n < 4; ++n)
#pragma unroll
        for (int r = 0; r < 4; ++r) o[n][r] *= fr[r];
      bf16x8 ap = *reinterpret_cast<const bf16x8*>(&pl[(w16 + lc) * 40 + (l16 << 3)]);
#pragma unroll
      for (int n = 0; n < 4; ++n) {
        bf16x8 bv = *reinterpret_cast<const bf16x8*>(&vt[cur][((n << 4) + lc) * 40 + (l16 << 3)]);
        o[n] = mfma16(ap, bv, o[n]);
      }
    }

    // ---- write-late V for t+1, rotate regs, single barrier ----
    if (t < 63) {
      writeV(nxt, ra_n, rb_n);
      segA_c = segA_n; segB_c = segB_n; pmA_c = pmA_n; pmB_c = pmB_n;
    }
    __syncthreads();
    cur = nxt;
  }

  // ---- epilogue ----
  if (l16 == 0) lroww[myq] = lrow;
  {
    float inv[4];
#pragma unroll
    for (int r = 0; r < 4; ++r)
      inv[r] = 1.f / (lroww[w16 + (l16 << 2) + r] + 1e-7f);
#pragma unroll
    for (int n = 0; n < 4; ++n) {
#pragma unroll
      for (int r = 0; r < 4; ++r) {
        const int row = qi0 + w16 + (l16 << 2) + r;
        const float v = o[n][r] * inv[r];
        const bf16 hi = (bf16)v;
        const float lof = v - (float)hi;
        const size_t off = (((size_t)(b << 10) + row) << 10) + (h << 6) + (n << 4) + lc;
        a_hi[off] = hi;
        a_lo[off] = (bf16)lof;
      }
    }
  }
}

// ---------------------------------------------------------------------------
extern "C" void kernel_launch(void* const* d_in, const int* in_sizes, int n_in,
                              void* d_out, int out_size, void* d_ws, size_t ws_size,
                              hipStream_t stream) {
  (void)in_sizes; (void)n_in; (void)out_size; (void)ws_size;
  const float* inputs    = (const float*)d_in[0];
  const float* content   = (const float*)d_in[1];
  const float* memories  = (const float*)d_in[2];
  const float* relatives = (const float*)d_in[3];
  const float* seg_mat   = (const float*)d_in[4];
  const float* seg_embed = (const float*)d_in[5];
  const float* bias_c    = (const float*)d_in[6];
  const float* bias_r    = (const float*)d_in[7];
  const float* bias_s    = (const float*)d_in[8];
  const float* perm      = (const float*)d_in[9];
  const float* kern      = (const float*)d_in[10];
  float* out = (float*)d_out;

  char* ws = (char*)d_ws;
  bf16*  in_b   = (bf16*)(ws);                 // [0, 4 MB)        dead after w_q GEMM
  bf16*  full_b = (bf16*)(ws + 4194304);       // [4, 12.58 MB)    dead after w_kv GEMM
  bf16*  rel_b  = (bf16*)(ws + 12582912);      // [12.58, 21.23)   dead after w_r GEMM
  bf16*  kT     = (bf16*)(ws + 21233664);
  bf16*  w_q    = (bf16*)(ws + 31719424);
  bf16*  w_k    = (bf16*)(ws + 35913728);
  bf16*  w_v    = (bf16*)(ws + 44302336);
  bf16*  w_rh   = (bf16*)(ws + 52690944);
  bf16*  a_hi   = (bf16*)(ws + 61083648);
  float* qs     = (float*)(ws + 65277952);
  // reuse dead prep space:
  bf16*  seg_b  = (bf16*)(ws);                 // 16.78 MB over in_b+full_b+rel_b head
  bf16*  a_lo   = (bf16*)(ws + 16777216);      // 4.19 MB in rel_b tail

  dim3 blk(256);
  cvt_bf16<<<2048, blk, 0, stream>>>(inputs, in_b, 2097152);
  cvt_full<<<4096, blk, 0, stream>>>(memories, content, full_b);
  cvt_bf16<<<4098, blk, 0, stream>>>(relatives, rel_b, 4196352);
  kT_cvt<<<dim3(80, 16), blk, 0, stream>>>(kern, kT);

  gemm_mfma<1><<<dim3(8, 16),  blk, 0, stream>>>(in_b,   kT,           w_q,  w_q, 2048, 1 << 30);
  gemm_mfma<1><<<dim3(16, 32), blk, 0, stream>>>(full_b, kT + 1048576, w_k,  w_v, 4096, 1024);
  gemm_mfma<1><<<dim3(8, 33),  blk, 0, stream>>>(rel_b,  kT + 3145728, w_rh, w_rh, 4098, 1 << 30);
  seg_proj<<<128, blk, 0, stream>>>(w_q, bias_s, seg_embed, qs);
  // after projections: in_b/full_b/rel_b dead -> convert seg_mat into that space
  cvt_seg<<<4096, blk, 0, stream>>>(seg_mat, seg_b);

  attn_mfma<<<512, blk, 0, stream>>>(w_q, w_k, w_v, w_rh, qs, seg_b, perm,
                                     bias_c, bias_r, a_hi, a_lo);

  gemm_mfma<0><<<dim3(8, 16), blk, 0, stream>>>(a_hi, kT + 4194304, out, out, 2048, 1 << 30);
  gemm_mfma<2><<<dim3(8, 16), blk, 0, stream>>>(a_lo, kT + 4194304, out, out, 2048, 1 << 30);
}

// Round 6
// 269.270 us; speedup vs baseline: 7.4665x; 1.1062x over previous
//
#include <hip/hip_runtime.h>

typedef __bf16 bf16;
typedef unsigned short u16;
typedef unsigned int u32;
typedef __attribute__((ext_vector_type(8))) __bf16 bf16x8;
typedef __attribute__((ext_vector_type(4))) __bf16 bf16x4;
typedef __attribute__((ext_vector_type(4))) float f32x4;
typedef __attribute__((ext_vector_type(8))) float f32x8;

// slot index (16B units) for 8-seg rows (64 bf16/row), XOR-swizzled
#define SWZ(r, s) (((r) << 3) + ((s) ^ ((r) & 7)))
// slot index for 4-seg rows (32 bf16/row), XOR-swizzled
#define GSW(r, s) (((r) << 2) + ((s) ^ (((r) >> 1) & 3)))

__device__ __forceinline__ f32x4 mfma16(bf16x8 a, bf16x8 b, f32x4 c) {
  return __builtin_amdgcn_mfma_f32_16x16x32_bf16(a, b, c, 0, 0, 0);
}
__device__ __forceinline__ void gld16(const void* g, void* l) {
  __builtin_amdgcn_global_load_lds((const __attribute__((address_space(1))) void*)g,
                                   (__attribute__((address_space(3))) void*)l, 16, 0, 0);
}

// ---------------------------------------------------------------------------
// prep_all: all input conversions + kernel transpose in ONE launch.
// 8 elems/thread => 2048 elems/block.
// blocks [0,1024):    inputs->bf16                  (2,097,152 elems)
// blocks [1024,3072): full=concat(mem,cont)->bf16   (4,194,304 elems)
// blocks [3072,5121): relatives->bf16               (4,196,352 elems)
// blocks [5121,6401): kT transpose+cvt              (1280 tile-blocks)
// ---------------------------------------------------------------------------
__global__ __launch_bounds__(256) void prep_all(
    const float* __restrict__ inputs, const float* __restrict__ mem,
    const float* __restrict__ cont, const float* __restrict__ rel,
    const float* __restrict__ K, bf16* __restrict__ in_b,
    bf16* __restrict__ full_b, bf16* __restrict__ rel_b, bf16* __restrict__ KT) {
  __shared__ float t[64][68];
  const int bid = blockIdx.x, tid = threadIdx.x;
  if (bid < 1024) {
    size_t i = ((size_t)bid * 256 + tid) * 8;
    f32x8 v = *reinterpret_cast<const f32x8*>(inputs + i);
    *reinterpret_cast<bf16x8*>(in_b + i) = __builtin_convertvector(v, bf16x8);
  } else if (bid < 3072) {
    size_t i = ((size_t)(bid - 1024) * 256 + tid) * 8;
    int row = (int)(i >> 10), col = (int)(i & 1023);
    int b = row >> 11, r = row & 2047;
    const float* src = (r < 1024)
        ? (mem  + (((size_t)(b << 10) + r)          << 10) + col)
        : (cont + (((size_t)(b << 10) + (r - 1024)) << 10) + col);
    f32x8 v = *reinterpret_cast<const f32x8*>(src);
    *reinterpret_cast<bf16x8*>(full_b + i) = __builtin_convertvector(v, bf16x8);
  } else if (bid < 5121) {
    size_t i = ((size_t)(bid - 3072) * 256 + tid) * 8;
    f32x8 v = *reinterpret_cast<const f32x8*>(rel + i);
    *reinterpret_cast<bf16x8*>(rel_b + i) = __builtin_convertvector(v, bf16x8);
  } else {
    const int r = bid - 5121;
    const int n0 = (r % 80) << 6, k0 = (r / 80) << 6;
    for (int idx = tid; idx < 1024; idx += 256) {
      int rr = idx >> 4, c4 = (idx & 15) << 2;
      f32x4 v = *reinterpret_cast<const f32x4*>(K + (size_t)(k0 + rr) * 5120 + n0 + c4);
      t[rr][c4] = v.x; t[rr][c4 + 1] = v.y; t[rr][c4 + 2] = v.z; t[rr][c4 + 3] = v.w;
    }
    __syncthreads();
    for (int idx = tid; idx < 1024; idx += 256) {
      int rr = idx >> 4, c4 = (idx & 15) << 2;
      bf16x4 o = { (bf16)t[c4][rr], (bf16)t[c4 + 1][rr], (bf16)t[c4 + 2][rr], (bf16)t[c4 + 3][rr] };
      *reinterpret_cast<bf16x4*>(KT + (size_t)(n0 + rr) * 1024 + k0 + c4) = o;
    }
  }
}

// ---------------------------------------------------------------------------
// generic MFMA GEMM body. MT in {64,128} rows; 128 cols; K = KLEN (A stride);
// KWRAP: BT k-index wraps at 1024 (for the hi|lo concat out-projection).
// ---------------------------------------------------------------------------
template<int MT, int OUT_MODE, int KLEN, bool KWRAP>
__device__ __forceinline__ void gemm_body(
    const bf16* __restrict__ A, const bf16* __restrict__ BT,
    void* __restrict__ C0v, void* __restrict__ C1v,
    int m0, int n0, int Mrows, int splitN, bf16* As, bf16* Bs, int tid) {
  const int l = tid & 63, w = tid >> 6;
  const int wn = (w & 1) << 6;
  const int wm = (w >> 1) * (MT / 2);
  constexpr int MFR = MT / 32;
  const int lc = l & 15, l16 = l >> 4;
  f32x4 acc[MFR][4] = {};
  const int r0 = tid >> 2;
  const int sq = tid & 3;
  const int g0 = (sq ^ ((r0 >> 1) & 3)) << 3;

  for (int k0 = 0; k0 < KLEN; k0 += 32) {
    const int kk = KWRAP ? (k0 & 1023) : k0;
    __syncthreads();
    gld16(A  + (size_t)(m0 + r0) * KLEN + k0 + g0, &As[tid << 3]);
    gld16(BT + (size_t)(n0 + r0) * 1024 + kk + g0, &Bs[tid << 3]);
    if (MT == 128)
      gld16(A + (size_t)(m0 + r0 + 64) * KLEN + k0 + g0, &As[(tid + 256) << 3]);
    gld16(BT + (size_t)(n0 + r0 + 64) * 1024 + kk + g0, &Bs[(tid + 256) << 3]);
    __syncthreads();
    bf16x8 af[MFR], bfv[4];
#pragma unroll
    for (int m = 0; m < MFR; ++m)
      af[m] = *reinterpret_cast<const bf16x8*>(&As[GSW(wm + (m << 4) + lc, l16) << 3]);
#pragma unroll
    for (int n = 0; n < 4; ++n)
      bfv[n] = *reinterpret_cast<const bf16x8*>(&Bs[GSW(wn + (n << 4) + lc, l16) << 3]);
#pragma unroll
    for (int m = 0; m < MFR; ++m)
#pragma unroll
      for (int n = 0; n < 4; ++n)
        acc[m][n] = mfma16(af[m], bfv[n], acc[m][n]);
  }
#pragma unroll
  for (int m = 0; m < MFR; ++m) {
    const int rbase = m0 + wm + (m << 4) + (l16 << 2);
#pragma unroll
    for (int n = 0; n < 4; ++n) {
      const int col = n0 + wn + (n << 4) + lc;
      const int cc = (col < splitN) ? col : (col - splitN);
      void* Cv = (col < splitN) ? C0v : C1v;
#pragma unroll
      for (int r = 0; r < 4; ++r) {
        const int row = rbase + r;
        if (row < Mrows) {
          const float v = acc[m][n][r];
          const size_t off = ((size_t)row << 10) + cc;
          if (OUT_MODE == 1) ((bf16*)Cv)[off] = (bf16)v;
          else               ((float*)Cv)[off] = v;
        }
      }
    }
  }
}

// all three projection GEMMs in one launch (1288 blocks)
__global__ __launch_bounds__(256) void proj_fused(
    const bf16* __restrict__ in_b, const bf16* __restrict__ full_b,
    const bf16* __restrict__ rel_b, const bf16* __restrict__ kT,
    bf16* __restrict__ w_q, bf16* __restrict__ w_k, bf16* __restrict__ w_v,
    bf16* __restrict__ w_rh) {
  __shared__ bf16 As[4096];
  __shared__ bf16 Bs[4096];
  const int bid = blockIdx.x, tid = threadIdx.x;
  if (bid < 256) {          // w_q: 32m(64) x 8n
    gemm_body<64, 1, 1024, false>(in_b, kT, w_q, w_q,
                                  (bid >> 3) << 6, (bid & 7) << 7, 2048, 1 << 30, As, Bs, tid);
  } else if (bid < 768) {   // w_kv: 32m(128) x 16n
    const int r = bid - 256;
    gemm_body<128, 1, 1024, false>(full_b, kT + (1 << 20), w_k, w_v,
                                   (r >> 4) << 7, (r & 15) << 7, 4096, 1024, As, Bs, tid);
  } else {                  // w_r: 65m(64) x 8n
    const int r = bid - 768;
    gemm_body<64, 1, 1024, false>(rel_b, kT + 3 * (1 << 20), w_rh, w_rh,
                                  (r >> 3) << 6, (r & 7) << 7, 4098, 1 << 30, As, Bs, tid);
  }
}

// out = a_cat(K=2048: hi|lo) @ [k_o;k_o]  (256 blocks, 64-row tiles)
__global__ __launch_bounds__(256) void out_proj(
    const bf16* __restrict__ a_cat, const bf16* __restrict__ kTo,
    float* __restrict__ out) {
  __shared__ bf16 As[4096];
  __shared__ bf16 Bs[4096];
  const int bid = blockIdx.x, tid = threadIdx.x;
  gemm_body<64, 0, 2048, true>(a_cat, kTo, out, out,
                               (bid >> 3) << 6, (bid & 7) << 7, 2048, 1 << 30, As, Bs, tid);
}

// ---------------------------------------------------------------------------
// mid_prep: seg_mat->bf16 (4096 blocks) + seg_proj (128 blocks)
// ---------------------------------------------------------------------------
__global__ __launch_bounds__(256) void mid_prep(
    const float* __restrict__ seg_mat, bf16* __restrict__ seg_b,
    const bf16* __restrict__ w_q, const float* __restrict__ bias_s,
    const float* __restrict__ seg_embed, float* __restrict__ qs) {
  const int bid = blockIdx.x, tid = threadIdx.x;
  if (bid < 4096) {
    size_t i = ((size_t)bid * 256 + tid) * 8;
    f32x8 v = *reinterpret_cast<const f32x8*>(seg_mat + i);
    *reinterpret_cast<bf16x8*>(seg_b + i) = __builtin_convertvector(v, bf16x8);
  } else {
    int idx = (bid - 4096) * 256 + tid;
    int q = idx & 1023, h = (idx >> 10) & 15, b = idx >> 14;
    const bf16* wp = w_q + (((size_t)(b << 10) + q) << 10) + (h << 6);
    const float* bp = bias_s + (h << 6);
    const float* e0 = seg_embed + (h << 6);
    const float* e1 = seg_embed + 1024 + (h << 6);
    float s0 = 0.f, s1 = 0.f;
#pragma unroll 8
    for (int d = 0; d < 64; ++d) {
      float v = (float)wp[d] + bp[d];
      s0 = fmaf(v, e0[d], s0);
      s1 = fmaf(v, e1[d], s1);
    }
    qs[((size_t)idx << 1) + 0] = s0;
    qs[((size_t)idx << 1) + 1] = s1;
  }
}

// ---------------------------------------------------------------------------
// fused attention: 2-phase double-buffered pipeline, Q in registers,
// rolling circular w_r band, setprio around MFMA clusters.
// rel shift: diff=j_g-i_g; diff<=1024 -> q_r[i].w_r[diff+1024]
//            diff>=1025 -> q_r[i+1].w_r[diff-1025]
// ---------------------------------------------------------------------------
#define OFFA 7
#define OFFB 0

__global__ __launch_bounds__(256) void attn_mfma(
    const bf16* __restrict__ w_q, const bf16* __restrict__ w_k,
    const bf16* __restrict__ w_v, const bf16* __restrict__ w_rh,
    const float* __restrict__ qs_seg, const bf16* __restrict__ seg_b,
    const float* __restrict__ perm, const float* __restrict__ bias_c,
    const float* __restrict__ bias_r, bf16* __restrict__ a_cat) {
  const int id = blockIdx.x;
  const int h  = (id >> 3) & 15;
  const int cg = (id & 7) | ((id >> 7) << 3);
  const int qt = cg & 15, b = cg >> 4;
  const int qi0 = qt << 6;
  const int tid = threadIdx.x;
  const int w = tid >> 6, l = tid & 63;
  const int lc = l & 15, l16 = l >> 4;
  const int w16 = w << 4;
  const int myq = w16 + lc;

  __shared__ bf16 kt[2][32 * 64];
  __shared__ u16  vt[2][64 * 40];
  __shared__ bf16 wbc[128 * 64];
  __shared__ bf16 wb2[96 * 64];
  __shared__ u16  pl[64 * 40];
  __shared__ float ART[4 * 960];
  __shared__ float facw[64], lroww[64];

  auto stageK = [&](int buf, int kj) {
    int r = tid >> 3, s = tid & 7;
    gld16(w_k + ((size_t)((b << 11) + kj + r) << 10) + (h << 6) + ((s ^ (r & 7)) << 3),
          &kt[buf][tid << 3]);
  };
  auto stageWB = [&](int L0, int nrows, int OFF) {
    for (int base = 0; base < nrows; base += 32) {
      int r = (tid >> 3) + base, s = tid & 7;
      int L = L0 + r;
      int slot = (L + OFF) & 127;
      int grow = L > 2048 ? 2048 : L;
      gld16(w_rh + ((size_t)(b * 2049 + grow) << 10) + (h << 6) + ((s ^ (slot & 7)) << 3),
            &wbc[((slot << 3) | s) << 3]);
    }
  };
  auto stageWB2 = [&]() {
    for (int base = 0; base < 96; base += 32) {
      int r = (tid >> 3) + base, s = tid & 7;
      gld16(w_rh + ((size_t)(b * 2049 + r) << 10) + (h << 6) + ((s ^ (r & 7)) << 3),
            &wb2[((r << 3) | s) << 3]);
    }
  };
  const int kv2 = (tid & 15) << 1, d4 = ((tid >> 4) & 15) << 2, kw = tid & 15;
  auto loadV = [&](int kj, uint2& ra, uint2& rb) {
    const u16* vp = (const u16*)w_v + ((size_t)((b << 11) + kj + kv2) << 10) + (h << 6) + d4;
    ra = *reinterpret_cast<const uint2*>(vp);
    rb = *reinterpret_cast<const uint2*>(vp + 1024);
  };
  auto writeV = [&](int buf, uint2 ra, uint2 rb) {
    u32* vt32 = reinterpret_cast<u32*>(&vt[buf][0]);
    vt32[(d4 + 0) * 20 + kw] = (ra.x & 0xffffu) | (rb.x << 16);
    vt32[(d4 + 1) * 20 + kw] = (ra.x >> 16) | (rb.x & 0xffff0000u);
    vt32[(d4 + 2) * 20 + kw] = (ra.y & 0xffffu) | (rb.y << 16);
    vt32[(d4 + 3) * 20 + kw] = (ra.y >> 16) | (rb.y & 0xffff0000u);
  };
  const size_t qrowg = (size_t)((b << 10) + qi0 + myq);
  auto loadSP = [&](int kj, bf16x8& sA, bf16x8& sB, f32x4& pA, f32x4& pB) {
    const bf16* sp = seg_b + (qrowg * 2048 + kj + (l16 << 2)) * 2;
    sA = *reinterpret_cast<const bf16x8*>(sp);
    sB = *reinterpret_cast<const bf16x8*>(sp + 32);
    const float* pp = perm + qrowg * 2048 + kj + (l16 << 2);
    pA = *reinterpret_cast<const f32x4*>(pp);
    pB = *reinterpret_cast<const f32x4*>(pp + 16);
  };

  stageK(0, 0);
  stageWB(961 - qi0, 96, OFFA);
  uint2 ra0, rb0;
  loadV(0, ra0, rb0);
  bf16x8 segA_c, segB_c, segA_n = {}, segB_n = {};
  f32x4 pmA_c, pmB_c, pmA_n = {}, pmB_n = {};
  loadSP(0, segA_c, segB_c, pmA_c, pmB_c);

  const int dlo = l16 << 3;
  bf16x8 qcf0, qcf1, qrf0, qrf1, qrg0, qrg1;
  {
    const bf16* qb  = w_q + ((qrowg) << 10) + (h << 6);
    const int rq1 = (qi0 + myq + 1 > 1023) ? 1023 : qi0 + myq + 1;
    const bf16* qb1 = w_q + (((size_t)(b << 10) + rq1) << 10) + (h << 6);
    f32x8 bc0 = *reinterpret_cast<const f32x8*>(bias_c + (h << 6) + dlo);
    f32x8 bc1 = *reinterpret_cast<const f32x8*>(bias_c + (h << 6) + 32 + dlo);
    f32x8 br0 = *reinterpret_cast<const f32x8*>(bias_r + (h << 6) + dlo);
    f32x8 br1 = *reinterpret_cast<const f32x8*>(bias_r + (h << 6) + 32 + dlo);
    bf16x8 q0 = *reinterpret_cast<const bf16x8*>(qb + dlo);
    bf16x8 q1 = *reinterpret_cast<const bf16x8*>(qb + 32 + dlo);
    bf16x8 p0 = *reinterpret_cast<const bf16x8*>(qb1 + dlo);
    bf16x8 p1 = *reinterpret_cast<const bf16x8*>(qb1 + 32 + dlo);
    qcf0 = __builtin_convertvector(__builtin_convertvector(q0, f32x8) + bc0, bf16x8);
    qcf1 = __builtin_convertvector(__builtin_convertvector(q1, f32x8) + bc1, bf16x8);
    qrf0 = __builtin_convertvector(__builtin_convertvector(q0, f32x8) + br0, bf16x8);
    qrf1 = __builtin_convertvector(__builtin_convertvector(q1, f32x8) + br1, bf16x8);
    qrg0 = __builtin_convertvector(__builtin_convertvector(p0, f32x8) + br0, bf16x8);
    qrg1 = __builtin_convertvector(__builtin_convertvector(p1, f32x8) + br1, bf16x8);
  }
  const float* qp = qs_seg + ((((size_t)((b << 4) + h) << 10) + qi0 + myq) << 1);
  const float qs0 = qp[0], qs1 = qp[1];

  writeV(0, ra0, rb0);
  __syncthreads();

  float mrow = -1e30f, lrow = 0.f;
  f32x4 o[4] = {};
  const float SCL = 0.125f * 1.44269504f;
  int cur = 0;
  uint2 ra_n = {}, rb_n = {};

  for (int t = 0; t < 64; ++t) {
    const int kj = t << 5;
    const int rel0 = kj - qi0;
    const bool strad = (rel0 == 1024) | (rel0 == 1056);
    const bool mainB = (rel0 >= 1088);
    const int nxt = cur ^ 1;

    if (t < 63) {
      const int kjn = kj + 32, rel0n = rel0 + 32;
      stageK(nxt, kjn);
      if (rel0n == 1024) stageWB2();
      if (rel0n == 1120)      stageWB(32, 96, OFFB);
      else if (rel0n != 1088) {
        if (rel0n <= 1056) stageWB(rel0n + 1025, 32, OFFA);
        else               stageWB(rel0n - 1024, 32, OFFB);
      }
      loadV(kjn, ra_n, rb_n);
      loadSP(kjn, segA_n, segB_n, pmA_n, pmB_n);
    }

    // context scores (swapped): D[k'][q=lc]
    f32x4 s0 = {0.f, 0.f, 0.f, 0.f}, s1 = {0.f, 0.f, 0.f, 0.f};
    {
      const bf16* ktc = kt[cur];
      bf16x8 a0 = *reinterpret_cast<const bf16x8*>(&ktc[SWZ(lc, l16) << 3]);
      bf16x8 a1 = *reinterpret_cast<const bf16x8*>(&ktc[SWZ(lc, l16 + 4) << 3]);
      bf16x8 a2 = *reinterpret_cast<const bf16x8*>(&ktc[SWZ(16 + lc, l16) << 3]);
      bf16x8 a3 = *reinterpret_cast<const bf16x8*>(&ktc[SWZ(16 + lc, l16 + 4) << 3]);
      __builtin_amdgcn_s_setprio(1);
      s0 = mfma16(a0, qcf0, s0); s0 = mfma16(a1, qcf1, s0);
      s1 = mfma16(a2, qcf0, s1); s1 = mfma16(a3, qcf1, s1);
      __builtin_amdgcn_s_setprio(0);
    }

    // relative term via ART[bandcol][q] + diagonal gather
    float relv[8];
    {
      const bf16x8 ar0 = mainB ? qrg0 : qrf0;
      const bf16x8 ar1 = mainB ? qrg1 : qrf1;
      const bool useWb2 = (rel0 == 1088);
      int sbase;
      if (!mainB)       sbase = (rel0 + 1016 - w16) & 127;
      else if (useWb2)  sbase = 48 - w16;
      else              sbase = (rel0 - 1040 - w16) & 127;
      const bf16* wbp = useWb2 ? wb2 : wbc;
#pragma unroll
      for (int bg = 0; bg < 3; ++bg) {
        int prow = sbase + (bg << 4) + lc;
        if (!useWb2) prow &= 127;
        bf16x8 w0 = *reinterpret_cast<const bf16x8*>(&wbp[SWZ(prow, l16) << 3]);
        bf16x8 w1 = *reinterpret_cast<const bf16x8*>(&wbp[SWZ(prow, l16 + 4) << 3]);
        f32x4 a_ = {0.f, 0.f, 0.f, 0.f};
        __builtin_amdgcn_s_setprio(1);
        a_ = mfma16(ar0, w0, a_); a_ = mfma16(ar1, w1, a_);
        __builtin_amdgcn_s_setprio(0);
        *reinterpret_cast<f32x4*>(&ART[w * 960 + ((bg << 4) + lc) * 20 + (l16 << 2)]) = a_;
      }
#pragma unroll
      for (int jj = 0; jj < 4; ++jj) {
        relv[jj]     = ART[w * 960 + (15 + (l16 << 2) + jj - lc) * 20 + lc];
        relv[4 + jj] = ART[w * 960 + (31 + (l16 << 2) + jj - lc) * 20 + lc];
      }
      if (strad) {
#pragma unroll
        for (int bg = 0; bg < 3; ++bg) {
          int srow = rel0 - 1040 - w16 + (bg << 4) + lc;
          srow = srow < 0 ? 0 : (srow > 95 ? 95 : srow);
          bf16x8 w0 = *reinterpret_cast<const bf16x8*>(&wb2[SWZ(srow, l16) << 3]);
          bf16x8 w1 = *reinterpret_cast<const bf16x8*>(&wb2[SWZ(srow, l16 + 4) << 3]);
          f32x4 a_ = {0.f, 0.f, 0.f, 0.f};
          a_ = mfma16(qrg0, w0, a_); a_ = mfma16(qrg1, w1, a_);
          *reinterpret_cast<f32x4*>(&ART[w * 960 + ((bg << 4) + lc) * 20 + (l16 << 2)]) = a_;
        }
#pragma unroll
        for (int jj = 0; jj < 4; ++jj) {
          const int jA = (l16 << 2) + jj, jB = 16 + jA;
          float rbA = ART[w * 960 + (15 + jA - lc) * 20 + lc];
          float rbB = ART[w * 960 + (15 + jB - lc) * 20 + lc];
          if (rel0 + jA - myq >= 1025) relv[jj] = rbA;
          if (rel0 + jB - myq >= 1025) relv[4 + jj] = rbB;
        }
      }
    }

    // in-register online softmax
    {
      f32x8 sgA = __builtin_convertvector(segA_c, f32x8);
      f32x8 sgB = __builtin_convertvector(segB_c, f32x8);
      float sv[8];
#pragma unroll
      for (int jj = 0; jj < 4; ++jj) {
        sv[jj]     = (s0[jj] + relv[jj]     + sgA[2 * jj] * qs0 + sgA[2 * jj + 1] * qs1) * SCL;
        sv[4 + jj] = (s1[jj] + relv[4 + jj] + sgB[2 * jj] * qs0 + sgB[2 * jj + 1] * qs1) * SCL;
      }
      float tm = sv[0];
#pragma unroll
      for (int jj = 1; jj < 8; ++jj) tm = fmaxf(tm, sv[jj]);
      tm = fmaxf(tm, __shfl_xor(tm, 16));
      tm = fmaxf(tm, __shfl_xor(tm, 32));
      const float mn2 = fmaxf(mrow, tm);
      const float facr = exp2f(mrow - mn2);
      float e[8], rs = 0.f;
#pragma unroll
      for (int jj = 0; jj < 4; ++jj) {
        e[jj]     = exp2f(sv[jj] - mn2) * pmA_c[jj];
        e[4 + jj] = exp2f(sv[4 + jj] - mn2) * pmB_c[jj];
        rs += e[jj] + e[4 + jj];
      }
      rs += __shfl_xor(rs, 16);
      rs += __shfl_xor(rs, 32);
      mrow = mn2;
      lrow = lrow * facr + rs;
      bf16x4 pa, pb;
#pragma unroll
      for (int jj = 0; jj < 4; ++jj) { pa[jj] = (bf16)e[jj]; pb[jj] = (bf16)e[4 + jj]; }
      *reinterpret_cast<bf16x4*>(&pl[myq * 40 + (l16 << 2)]) = pa;
      *reinterpret_cast<bf16x4*>(&pl[myq * 40 + 16 + (l16 << 2)]) = pb;
      if (l16 == 0) facw[myq] = facr;
    }

    // PV
    {
      float fr[4];
#pragma unroll
      for (int r = 0; r < 4; ++r) fr[r] = facw[w16 + (l16 << 2) + r];
#pragma unroll
      for (int n = 0; n < 4; ++n)
#pragma unroll
        for (int r = 0; r < 4; ++r) o[n][r] *= fr[r];
      bf16x8 ap = *reinterpret_cast<const bf16x8*>(&pl[(w16 + lc) * 40 + (l16 << 3)]);
      bf16x8 bv0 = *reinterpret_cast<const bf16x8*>(&vt[cur][(lc) * 40 + (l16 << 3)]);
      bf16x8 bv1 = *reinterpret_cast<const bf16x8*>(&vt[cur][(16 + lc) * 40 + (l16 << 3)]);
      bf16x8 bv2 = *reinterpret_cast<const bf16x8*>(&vt[cur][(32 + lc) * 40 + (l16 << 3)]);
      bf16x8 bv3 = *reinterpret_cast<const bf16x8*>(&vt[cur][(48 + lc) * 40 + (l16 << 3)]);
      __builtin_amdgcn_s_setprio(1);
      o[0] = mfma16(ap, bv0, o[0]);
      o[1] = mfma16(ap, bv1, o[1]);
      o[2] = mfma16(ap, bv2, o[2]);
      o[3] = mfma16(ap, bv3, o[3]);
      __builtin_amdgcn_s_setprio(0);
    }

    if (t < 63) {
      writeV(nxt, ra_n, rb_n);
      segA_c = segA_n; segB_c = segB_n; pmA_c = pmA_n; pmB_c = pmB_n;
    }
    __syncthreads();
    cur = nxt;
  }

  // epilogue: normalize, hi|lo concat store (row stride 2048)
  if (l16 == 0) lroww[myq] = lrow;
  {
    float inv[4];
#pragma unroll
    for (int r = 0; r < 4; ++r)
      inv[r] = 1.f / (lroww[w16 + (l16 << 2) + r] + 1e-7f);
#pragma unroll
    for (int n = 0; n < 4; ++n) {
#pragma unroll
      for (int r = 0; r < 4; ++r) {
        const int row = qi0 + w16 + (l16 << 2) + r;
        const float v = o[n][r] * inv[r];
        const bf16 hi = (bf16)v;
        const float lof = v - (float)hi;
        const size_t off = (((size_t)(b << 10) + row) << 11) + (h << 6) + (n << 4) + lc;
        a_cat[off] = hi;
        a_cat[off + 1024] = (bf16)lof;
      }
    }
  }
}

// ---------------------------------------------------------------------------
extern "C" void kernel_launch(void* const* d_in, const int* in_sizes, int n_in,
                              void* d_out, int out_size, void* d_ws, size_t ws_size,
                              hipStream_t stream) {
  (void)in_sizes; (void)n_in; (void)out_size; (void)ws_size;
  const float* inputs    = (const float*)d_in[0];
  const float* content   = (const float*)d_in[1];
  const float* memories  = (const float*)d_in[2];
  const float* relatives = (const float*)d_in[3];
  const float* seg_mat   = (const float*)d_in[4];
  const float* seg_embed = (const float*)d_in[5];
  const float* bias_c    = (const float*)d_in[6];
  const float* bias_r    = (const float*)d_in[7];
  const float* bias_s    = (const float*)d_in[8];
  const float* perm      = (const float*)d_in[9];
  const float* kern      = (const float*)d_in[10];
  float* out = (float*)d_out;

  char* ws = (char*)d_ws;
  bf16*  in_b   = (bf16*)(ws);                 // [0, 4.19 MB)
  bf16*  full_b = (bf16*)(ws + 4194304);       // [4.19, 12.58 MB)
  bf16*  rel_b  = (bf16*)(ws + 12582912);      // [12.58, ~21.0 MB) + slack
  bf16*  kT     = (bf16*)(ws + 21233664);      // [21.23, 31.72 MB)
  bf16*  w_q    = (bf16*)(ws + 31719424);
  bf16*  w_k    = (bf16*)(ws + 35913728);
  bf16*  w_v    = (bf16*)(ws + 44302336);
  bf16*  w_rh   = (bf16*)(ws + 52690944);      // ends 61,083,648
  float* qs     = (float*)(ws + 65277952);
  // aliases of dead regions:
  bf16*  seg_b  = (bf16*)(ws);                 // over in_b..rel_b (dead after proj)
  bf16*  a_cat  = (bf16*)(ws + 21233664);      // over kT[k_q..k_r] (dead after proj)
  bf16*  kTo    = (bf16*)(ws + 29622272);      // kT rows 4096..5119 (k_o^T)

  dim3 blk(256);
  prep_all<<<6401, blk, 0, stream>>>(inputs, memories, content, relatives, kern,
                                     in_b, full_b, rel_b, kT);
  proj_fused<<<1288, blk, 0, stream>>>(in_b, full_b, rel_b, kT, w_q, w_k, w_v, w_rh);
  mid_prep<<<4224, blk, 0, stream>>>(seg_mat, seg_b, w_q, bias_s, seg_embed, qs);
  attn_mfma<<<512, blk, 0, stream>>>(w_q, w_k, w_v, w_rh, qs, seg_b, perm,
                                     bias_c, bias_r, a_cat);
  out_proj<<<256, blk, 0, stream>>>(a_cat, kTo, out);
}